// Round 10
// baseline (1605.959 us; speedup 1.0000x reference)
//
#include <hip/hip_runtime.h>
#include <cstdint>
#include <cstddef>

#define WG 256
#define NB 16  // batch

// Layout "L": arr[(n*16 + b)*F + f]  — node-major, batch, feature.

struct IP5 { const int* e[5]; };
struct Ptr3 { const float* p[3]; };

static __device__ __forceinline__ void fma4(float4& a, float s, const float4& b) {
  a.x = fmaf(s, b.x, a.x); a.y = fmaf(s, b.y, a.y);
  a.z = fmaf(s, b.z, a.z); a.w = fmaf(s, b.w, a.w);
}

// ---------------- fused setup kernels ----------------

__global__ void k_zero_i(int* __restrict__ p, int n) {
  int i = blockIdx.x * WG + threadIdx.x;
  if (i < n) p[i] = 0;
}

__global__ void k_hist_all(IP5 ep, int* __restrict__ dsrc, int* __restrict__ dtgt) {
  int i = blockIdx.x * WG + threadIdx.x;
  if (i >= 159852) return;
  int l, eo, ee, no, co;
  if (i < 120000)      { l = 0; eo = 0;      ee = 120000; no = 0;     co = 0; }
  else if (i < 150000) { l = 1; eo = 120000; ee = 30000;  no = 20000; co = 20000; }
  else if (i < 157500) { l = 2; eo = 150000; ee = 7500;   no = 25000; co = 25000; }
  else if (i < 159378) { l = 3; eo = 157500; ee = 1878;   no = 26250; co = 26250; }
  else                 { l = 4; eo = 159378; ee = 474;    no = 26563; co = 26563; }
  int e = i - eo;
  const int* E = ep.e[l];
  atomicAdd(&dsrc[no + E[e]], 1);
  atomicAdd(&dtgt[co + E[ee + e]], 1);
}

__global__ void k_scan_all(const int* __restrict__ deg_all, int* __restrict__ rowptr_all,
                           int* __restrict__ cursor_all) {
  static const int Ns[5] = {20000, 5000, 1250, 313, 20000};
  static const int CO[5] = {0, 20000, 25000, 26250, 26563};
  static const int RO[5] = {0, 20001, 25002, 26253, 26567};
  __shared__ int s[WG];
  int l = blockIdx.x;
  int N = Ns[l];
  const int* deg = deg_all + CO[l];
  int* rowptr = rowptr_all + RO[l];
  int* cursor = cursor_all + CO[l];
  int t = threadIdx.x;
  int chunk = (N + WG - 1) / WG;
  int a = t * chunk;
  int b = min(N, a + chunk);
  int sum = 0;
  for (int i = a; i < b; i++) sum += deg[i];
  s[t] = sum;
  __syncthreads();
  for (int off = 1; off < WG; off <<= 1) {
    int v = (t >= off) ? s[t - off] : 0;
    __syncthreads();
    s[t] += v;
    __syncthreads();
  }
  int run = (t == 0) ? 0 : s[t - 1];
  for (int i = a; i < b; i++) {
    rowptr[i] = run;
    cursor[i] = run;
    run += deg[i];
  }
  if (t == 0) rowptr[N] = s[WG - 1];
}

// ---------------- threefry eps (verified vs harness JAX ref) ----------------

static __device__ __forceinline__ float erfinv_f(float x) {
  float w = -log1pf(-x * x);
  float p;
  if (w < 5.0f) {
    w -= 2.5f;
    p = 2.81022636e-08f;
    p = fmaf(p, w, 3.43273939e-07f);
    p = fmaf(p, w, -3.5233877e-06f);
    p = fmaf(p, w, -4.39150654e-06f);
    p = fmaf(p, w, 0.00021858087f);
    p = fmaf(p, w, -0.00125372503f);
    p = fmaf(p, w, -0.00417768164f);
    p = fmaf(p, w, 0.246640727f);
    p = fmaf(p, w, 1.50140941f);
  } else {
    w = sqrtf(w) - 3.0f;
    p = -0.000200214257f;
    p = fmaf(p, w, 0.000100950558f);
    p = fmaf(p, w, 0.00134934322f);
    p = fmaf(p, w, -0.00367342844f);
    p = fmaf(p, w, 0.00573950773f);
    p = fmaf(p, w, -0.0076224613f);
    p = fmaf(p, w, 0.00943887047f);
    p = fmaf(p, w, 1.00167406f);
    p = fmaf(p, w, 2.83297682f);
  }
  return p * x;
}

static __device__ __forceinline__ float bits_to_normal(unsigned b) {
  float f = __uint_as_float((b >> 9) | 0x3f800000u) - 1.0f;
  const float lo = -0.99999994f;
  float u = f * (1.0f - lo) + lo;
  u = fmaxf(u, lo);
  return 1.41421356f * erfinv_f(u);
}

static __device__ __forceinline__ float eps_val(int i) {
  unsigned x0 = 0u, x1 = (unsigned)i;
  unsigned ks[3] = {0u, 42u, 0u ^ 42u ^ 0x1BD11BDAu};
  x0 += ks[0];
  x1 += ks[1];
  const int R[2][4] = {{13, 15, 26, 6}, {17, 29, 16, 24}};
#pragma unroll
  for (int it = 0; it < 5; it++) {
#pragma unroll
    for (int j = 0; j < 4; j++) {
      x0 += x1;
      int r = R[it & 1][j];
      x1 = (x1 << r) | (x1 >> (32 - r));
      x1 ^= x0;
    }
    x0 += ks[(it + 1) % 3];
    x1 += ks[(it + 2) % 3] + (unsigned)(it + 1);
  }
  return bits_to_normal(x0 ^ x1);
}

__global__ void k_fill_all(IP5 ep, const int* __restrict__ dsrc, int* __restrict__ cursor,
                           int* __restrict__ csrc, float* __restrict__ csw,
                           float* __restrict__ eps, const float* __restrict__ x,
                           float* __restrict__ sxl) {
  int blk = blockIdx.x;
  if (blk < 625) {
    int i = blk * WG + threadIdx.x;
    if (i >= 159852) return;
    int l, eo, ee, no, co, eb;
    if (i < 120000)      { l = 0; eo = 0;      ee = 120000; no = 0;     co = 0;     eb = 0; }
    else if (i < 150000) { l = 1; eo = 120000; ee = 30000;  no = 20000; co = 20000; eb = 120000; }
    else if (i < 157500) { l = 2; eo = 150000; ee = 7500;   no = 25000; co = 25000; eb = 150000; }
    else if (i < 159378) { l = 3; eo = 157500; ee = 1878;   no = 26250; co = 26250; eb = 157500; }
    else                 { l = 4; eo = 159378; ee = 474;    no = 26563; co = 26563; eb = 159378; }
    int e = i - eo;
    const int* E = ep.e[l];
    int s = E[e], t = E[ee + e];
    float da = (float)dsrc[no + s], db = (float)dsrc[no + t];
    float wa = (da > 0.f) ? (1.0f / sqrtf(da)) : 0.f;
    float wb = (db > 0.f) ? (1.0f / sqrtf(db)) : 0.f;
    int pos = atomicAdd(&cursor[co + t], 1);
    csrc[eb + pos] = s;
    csw[eb + pos] = wa * wb;
  } else if (blk < 629) {
    int j = (blk - 625) * WG + threadIdx.x;
    if (j < 1024) eps[j] = eps_val(j);
  } else {
    int j = (blk - 629) * WG + threadIdx.x;
    if (j >= NB * 20000 * 3) return;
    int f = j % 3;
    int b = (j / 3) % NB;
    int n = j / 48;
    sxl[j] = x[((size_t)b * 20000 + n) * 3 + f];
  }
}

// ---------------- wave-per-node Chebyshev propagation (4-edge unrolled) ----------------

#define RFL_I(v) __builtin_amdgcn_readfirstlane(v)
#define RFL_F(v) __int_as_float(__builtin_amdgcn_readfirstlane(__float_as_int(v)))

template <int F>
__global__ __launch_bounds__(WG) void k_propw(const float* __restrict__ in,
                                              float* __restrict__ out,
                                              const float* __restrict__ sub, float scale,
                                              const int* __restrict__ rowptr,
                                              const int* __restrict__ csrc,
                                              const float* __restrict__ csw, int N) {
  constexpr int C4 = F / 16;
  int node = blockIdx.x * 4 + (threadIdx.x >> 6);
  if (node >= N) return;
  int lane = threadIdx.x & 63;
  const float4* in4 = (const float4*)in;
  float4 acc[C4];
#pragma unroll
  for (int u = 0; u < C4; u++) acc[u] = make_float4(0.f, 0.f, 0.f, 0.f);
  int beg = rowptr[node], end = rowptr[node + 1];
  int j = beg;
  for (; j + 3 < end; j += 4) {
    int s0 = RFL_I(csrc[j]);
    int s1 = RFL_I(csrc[j + 1]);
    int s2 = RFL_I(csrc[j + 2]);
    int s3 = RFL_I(csrc[j + 3]);
    float w0 = RFL_F(csw[j]);
    float w1 = RFL_F(csw[j + 1]);
    float w2 = RFL_F(csw[j + 2]);
    float w3 = RFL_F(csw[j + 3]);
    const float4* p0 = in4 + (size_t)s0 * (4 * F) + lane;
    const float4* p1 = in4 + (size_t)s1 * (4 * F) + lane;
    const float4* p2 = in4 + (size_t)s2 * (4 * F) + lane;
    const float4* p3 = in4 + (size_t)s3 * (4 * F) + lane;
    float4 v0[C4], v1[C4], v2[C4], v3[C4];
#pragma unroll
    for (int u = 0; u < C4; u++) v0[u] = p0[u * 64];
#pragma unroll
    for (int u = 0; u < C4; u++) v1[u] = p1[u * 64];
#pragma unroll
    for (int u = 0; u < C4; u++) v2[u] = p2[u * 64];
#pragma unroll
    for (int u = 0; u < C4; u++) v3[u] = p3[u * 64];
#pragma unroll
    for (int u = 0; u < C4; u++) {
      fma4(acc[u], w0, v0[u]);
      fma4(acc[u], w1, v1[u]);
      fma4(acc[u], w2, v2[u]);
      fma4(acc[u], w3, v3[u]);
    }
  }
  for (; j < end; j++) {
    int s0 = RFL_I(csrc[j]);
    float w0 = RFL_F(csw[j]);
    const float4* p0 = in4 + (size_t)s0 * (4 * F) + lane;
#pragma unroll
    for (int u = 0; u < C4; u++) {
      float4 v0 = p0[u * 64];
      fma4(acc[u], w0, v0);
    }
  }
  float4* o4 = (float4*)out + (size_t)node * (4 * F) + lane;
  if (sub) {
    const float4* s4 = (const float4*)sub + (size_t)node * (4 * F) + lane;
#pragma unroll
    for (int u = 0; u < C4; u++) {
      float4 sv = s4[u * 64];
      float4 r;
      r.x = fmaf(scale, acc[u].x, -sv.x); r.y = fmaf(scale, acc[u].y, -sv.y);
      r.z = fmaf(scale, acc[u].z, -sv.z); r.w = fmaf(scale, acc[u].w, -sv.w);
      o4[u * 64] = r;
    }
  } else {
#pragma unroll
    for (int u = 0; u < C4; u++) {
      float4 r;
      r.x = scale * acc[u].x; r.y = scale * acc[u].y;
      r.z = scale * acc[u].z; r.w = scale * acc[u].w;
      o4[u * 64] = r;
    }
  }
}

// F=3 variant
__global__ __launch_bounds__(WG) void k_propw3(const float* __restrict__ in,
                                               float* __restrict__ out,
                                               const float* __restrict__ sub, float scale,
                                               const int* __restrict__ rowptr,
                                               const int* __restrict__ csrc,
                                               const float* __restrict__ csw, int N) {
  int node = blockIdx.x * 4 + (threadIdx.x >> 6);
  if (node >= N) return;
  int lane = threadIdx.x & 63;
  if (lane >= 48) return;
  float acc = 0.f;
  int beg = rowptr[node], end = rowptr[node + 1];
  for (int j = beg; j < end; j++) {
    int s = RFL_I(csrc[j]);
    float w = RFL_F(csw[j]);
    acc = fmaf(w, in[(size_t)s * 48 + lane], acc);
  }
  float r = scale * acc;
  if (sub) r -= sub[(size_t)node * 48 + lane];
  out[(size_t)node * 48 + lane] = r;
}

// ---------------- LDS-staged fused 3-term GEMM, G=32, 4 rows x 8 cols/thread ----
// Block of BS threads covers BS rows. x-tile staged coalesced into LDS with
// padded stride F+4 (2-way bank alias = free). Thread (cg=t&3, rtw=(t>>2)&15,
// wv=t>>6) computes rows wv*64+rtw+16r (r<4), cols cg*8..+7.

template <int F, int BS>
__global__ __launch_bounds__(BS) void k_gemm3s(Ptr3 txs, const float* __restrict__ W,
                                               const float* __restrict__ bias,
                                               float* __restrict__ out, int rows,
                                               const int* __restrict__ idx,
                                               int accum, int relu) {
  constexpr int PF = F + 4;
  constexpr int RPB = BS;
  __shared__ float sX[RPB * PF];
  __shared__ float sW[3 * F * 32];
  int tid = threadIdx.x;
  for (int i = tid; i < 3 * F * 32; i += BS) sW[i] = W[i];
  int row0 = blockIdx.x * RPB;
  int cg = tid & 3;
  int lr0 = (tid >> 6) * 64 + ((tid >> 2) & 15);
  float4 acc[4][2];
  if (accum) {
#pragma unroll
    for (int r = 0; r < 4; r++) {
      int gr = row0 + lr0 + 16 * r;
      if (gr < rows) {
        const float* o = out + (size_t)gr * 32 + cg * 8;
        acc[r][0] = *(const float4*)o;
        acc[r][1] = *(const float4*)(o + 4);
      } else {
        acc[r][0] = acc[r][1] = make_float4(0.f, 0.f, 0.f, 0.f);
      }
    }
  } else if (bias) {
    float4 b0 = *(const float4*)(bias + cg * 8);
    float4 b1 = *(const float4*)(bias + cg * 8 + 4);
#pragma unroll
    for (int r = 0; r < 4; r++) { acc[r][0] = b0; acc[r][1] = b1; }
  } else {
#pragma unroll
    for (int r = 0; r < 4; r++)
      acc[r][0] = acc[r][1] = make_float4(0.f, 0.f, 0.f, 0.f);
  }
  for (int kk = 0; kk < 3; kk++) {
    __syncthreads();
    const float* src = txs.p[kk];
    if (idx) {
      int node0 = row0 >> 4;
      for (int i = tid; i < RPB * F; i += BS) {
        int nl = i / (16 * F);
        int off = i - nl * (16 * F);
        int ng = node0 + nl;
        float v = 0.f;
        if (ng * 16 < rows) v = src[(size_t)idx[ng] * (16 * F) + off];
        int rr = i / F;
        sX[rr * PF + (i - rr * F)] = v;
      }
    } else {
      for (int i = tid; i < RPB * F; i += BS) {
        float v = 0.f;
        long g = (long)row0 * F + i;
        if (g < (long)rows * F) v = src[g];
        int rr = i / F;
        sX[rr * PF + (i - rr * F)] = v;
      }
    }
    __syncthreads();
    const float* wk = sW + kk * F * 32;
#pragma unroll
    for (int fg = 0; fg < F / 4; fg++) {
      float4 wA[4][2];
#pragma unroll
      for (int f = 0; f < 4; f++) {
        wA[f][0] = *(const float4*)(wk + (4 * fg + f) * 32 + cg * 8);
        wA[f][1] = *(const float4*)(wk + (4 * fg + f) * 32 + cg * 8 + 4);
      }
#pragma unroll
      for (int r = 0; r < 4; r++) {
        float4 xv = *(const float4*)(sX + (lr0 + 16 * r) * PF + 4 * fg);
        fma4(acc[r][0], xv.x, wA[0][0]); fma4(acc[r][1], xv.x, wA[0][1]);
        fma4(acc[r][0], xv.y, wA[1][0]); fma4(acc[r][1], xv.y, wA[1][1]);
        fma4(acc[r][0], xv.z, wA[2][0]); fma4(acc[r][1], xv.z, wA[2][1]);
        fma4(acc[r][0], xv.w, wA[3][0]); fma4(acc[r][1], xv.w, wA[3][1]);
      }
    }
  }
  if (relu) {
#pragma unroll
    for (int r = 0; r < 4; r++) {
      acc[r][0].x = fmaxf(acc[r][0].x, 0.f); acc[r][0].y = fmaxf(acc[r][0].y, 0.f);
      acc[r][0].z = fmaxf(acc[r][0].z, 0.f); acc[r][0].w = fmaxf(acc[r][0].w, 0.f);
      acc[r][1].x = fmaxf(acc[r][1].x, 0.f); acc[r][1].y = fmaxf(acc[r][1].y, 0.f);
      acc[r][1].z = fmaxf(acc[r][1].z, 0.f); acc[r][1].w = fmaxf(acc[r][1].w, 0.f);
    }
  }
#pragma unroll
  for (int r = 0; r < 4; r++) {
    int gr = row0 + lr0 + 16 * r;
    if (gr < rows) {
      float* o = out + (size_t)gr * 32 + cg * 8;
      *(float4*)o = acc[r][0];
      *(float4*)(o + 4) = acc[r][1];
    }
  }
}

// LDS-staged final: accum from out(s0) + relu + level-4 shortcut to dout.
// F=32, BS=256, rows multiple of 256 (320000 -> 1250 blocks).
__global__ __launch_bounds__(256) void k_gemm3s_final(Ptr3 txs, const float* __restrict__ W,
                                                      const float* __restrict__ W4,
                                                      float* __restrict__ out,
                                                      float* __restrict__ dout, int rows) {
  constexpr int F = 32, PF = 36, RPB = 256, BS = 256;
  __shared__ float sX[RPB * PF];
  __shared__ float sW[3 * F * 32];
  __shared__ float sWc[96];
  int tid = threadIdx.x;
  for (int i = tid; i < 3 * F * 32; i += BS) sW[i] = W[i];
  if (tid < 96) sWc[tid] = W4[tid] - W4[192 + tid] + W4[384 + tid];
  int row0 = blockIdx.x * RPB;
  int cg = tid & 3;
  int lr0 = (tid >> 6) * 64 + ((tid >> 2) & 15);
  float4 acc[4][2];
#pragma unroll
  for (int r = 0; r < 4; r++) {
    const float* o = out + (size_t)(row0 + lr0 + 16 * r) * 32 + cg * 8;
    acc[r][0] = *(const float4*)o;
    acc[r][1] = *(const float4*)(o + 4);
  }
  for (int kk = 0; kk < 3; kk++) {
    __syncthreads();
    const float* src = txs.p[kk] + (size_t)row0 * F;
    for (int i = tid; i < RPB * F; i += BS) {
      int rr = i / F;
      sX[rr * PF + (i - rr * F)] = src[i];
    }
    __syncthreads();
    const float* wk = sW + kk * F * 32;
#pragma unroll
    for (int fg = 0; fg < F / 4; fg++) {
      float4 wA[4][2];
#pragma unroll
      for (int f = 0; f < 4; f++) {
        wA[f][0] = *(const float4*)(wk + (4 * fg + f) * 32 + cg * 8);
        wA[f][1] = *(const float4*)(wk + (4 * fg + f) * 32 + cg * 8 + 4);
      }
#pragma unroll
      for (int r = 0; r < 4; r++) {
        float4 xv = *(const float4*)(sX + (lr0 + 16 * r) * PF + 4 * fg);
        fma4(acc[r][0], xv.x, wA[0][0]); fma4(acc[r][1], xv.x, wA[0][1]);
        fma4(acc[r][0], xv.y, wA[1][0]); fma4(acc[r][1], xv.y, wA[1][1]);
        fma4(acc[r][0], xv.z, wA[2][0]); fma4(acc[r][1], xv.z, wA[2][1]);
        fma4(acc[r][0], xv.w, wA[3][0]); fma4(acc[r][1], xv.w, wA[3][1]);
      }
    }
  }
#pragma unroll
  for (int r = 0; r < 4; r++) {
    acc[r][0].x = fmaxf(acc[r][0].x, 0.f); acc[r][0].y = fmaxf(acc[r][0].y, 0.f);
    acc[r][0].z = fmaxf(acc[r][0].z, 0.f); acc[r][0].w = fmaxf(acc[r][0].w, 0.f);
    acc[r][1].x = fmaxf(acc[r][1].x, 0.f); acc[r][1].y = fmaxf(acc[r][1].y, 0.f);
    acc[r][1].z = fmaxf(acc[r][1].z, 0.f); acc[r][1].w = fmaxf(acc[r][1].w, 0.f);
  }
  // s0 slice for final_fix (nodes < 79)
#pragma unroll
  for (int r = 0; r < 4; r++) {
    int gr = row0 + lr0 + 16 * r;
    if ((gr >> 4) < 79) {
      float* o = out + (size_t)gr * 32 + cg * 8;
      *(float4*)o = acc[r][0];
      *(float4*)(o + 4) = acc[r][1];
    }
  }
  // level-4 shortcut: per-thread 8-f partial, reduce across the 4 cg lanes
  float wc[8][3];
#pragma unroll
  for (int j = 0; j < 8; j++) {
    int f = cg * 8 + j;
    wc[j][0] = sWc[f * 3 + 0]; wc[j][1] = sWc[f * 3 + 1]; wc[j][2] = sWc[f * 3 + 2];
  }
#pragma unroll
  for (int r = 0; r < 4; r++) {
    float av[8] = {acc[r][0].x, acc[r][0].y, acc[r][0].z, acc[r][0].w,
                   acc[r][1].x, acc[r][1].y, acc[r][1].z, acc[r][1].w};
    float p0 = 0.f, p1 = 0.f, p2 = 0.f;
#pragma unroll
    for (int j = 0; j < 8; j++) {
      p0 = fmaf(av[j], wc[j][0], p0);
      p1 = fmaf(av[j], wc[j][1], p1);
      p2 = fmaf(av[j], wc[j][2], p2);
    }
    p0 += __shfl_xor(p0, 1, 64); p1 += __shfl_xor(p1, 1, 64); p2 += __shfl_xor(p2, 1, 64);
    p0 += __shfl_xor(p0, 2, 64); p1 += __shfl_xor(p1, 2, 64); p2 += __shfl_xor(p2, 2, 64);
    if (cg == 0) {
      int row = row0 + lr0 + 16 * r;
      int n = row >> 4, b = row & 15;
      float* od = dout + ((size_t)b * 20000 + n) * 3;
      od[0] = p0; od[1] = p1; od[2] = p2;
    }
  }
}

// ---------------- legacy fused 3-term GEMM (F=3 and G=64 shapes) ----------------

template <int F, int G>
__global__ __launch_bounds__(WG) void k_gemm3(Ptr3 txs, const float* __restrict__ W,
                                              const float* __restrict__ bias,
                                              float* __restrict__ out, int rows,
                                              const int* __restrict__ idx,
                                              int accum, int relu) {
  constexpr int CG = G / 4;
  constexpr int RT = WG / CG;
  constexpr int RPB = RT * 4;
  __shared__ float sW[3 * F * G];
  for (int i = threadIdx.x; i < 3 * F * G; i += WG) sW[i] = W[i];
  __syncthreads();
  int cg = threadIdx.x % CG;
  int rt = threadIdx.x / CG;
  int row0 = blockIdx.x * RPB + rt * 4;
  if (row0 >= rows) return;
  size_t src0 = row0;
  if (idx) {
    int node = row0 >> 4, b = row0 & 15;
    src0 = (size_t)idx[node] * 16 + b;
  }
  float* o = out + (size_t)row0 * G + cg * 4;
  float4 acc[4];
  if (accum) {
#pragma unroll
    for (int r = 0; r < 4; r++) acc[r] = *(const float4*)(o + (size_t)r * G);
  } else if (bias) {
    float4 bv = *(const float4*)(bias + cg * 4);
#pragma unroll
    for (int r = 0; r < 4; r++) acc[r] = bv;
  } else {
#pragma unroll
    for (int r = 0; r < 4; r++) acc[r] = make_float4(0.f, 0.f, 0.f, 0.f);
  }
#pragma unroll
  for (int kk = 0; kk < 3; kk++) {
    const float* tb = txs.p[kk] + src0 * F;
    const float* w = sW + kk * F * G + cg * 4;
    if constexpr (F == 3) {
      float4 w0 = *(const float4*)(w + 0 * G);
      float4 w1 = *(const float4*)(w + 1 * G);
      float4 w2 = *(const float4*)(w + 2 * G);
#pragma unroll
      for (int r = 0; r < 4; r++) {
        float x0 = tb[r * 3 + 0], x1 = tb[r * 3 + 1], x2 = tb[r * 3 + 2];
        fma4(acc[r], x0, w0);
        fma4(acc[r], x1, w1);
        fma4(acc[r], x2, w2);
      }
    } else {
#pragma unroll
      for (int fg = 0; fg < F / 4; fg++) {
        float4 xv[4];
#pragma unroll
        for (int r = 0; r < 4; r++) xv[r] = *(const float4*)(tb + (size_t)r * F + 4 * fg);
        float4 w0 = *(const float4*)(w + (4 * fg + 0) * G);
        float4 w1 = *(const float4*)(w + (4 * fg + 1) * G);
        float4 w2 = *(const float4*)(w + (4 * fg + 2) * G);
        float4 w3 = *(const float4*)(w + (4 * fg + 3) * G);
#pragma unroll
        for (int r = 0; r < 4; r++) {
          fma4(acc[r], xv[r].x, w0);
          fma4(acc[r], xv[r].y, w1);
          fma4(acc[r], xv[r].z, w2);
          fma4(acc[r], xv[r].w, w3);
        }
      }
    }
  }
  if (relu) {
#pragma unroll
    for (int r = 0; r < 4; r++) {
      acc[r].x = fmaxf(acc[r].x, 0.f); acc[r].y = fmaxf(acc[r].y, 0.f);
      acc[r].z = fmaxf(acc[r].z, 0.f); acc[r].w = fmaxf(acc[r].w, 0.f);
    }
  }
#pragma unroll
  for (int r = 0; r < 4; r++) *(float4*)(o + (size_t)r * G) = acc[r];
}

// exact K=6 fixup for the 79 real nodes; in is L layout. one block per batch.
__global__ __launch_bounds__(256) void k_final_fix(const float* __restrict__ in,
                                                   const float* __restrict__ W,  // 6x32x3
                                                   const int* __restrict__ rowptr,
                                                   const int* __restrict__ csrc,
                                                   const float* __restrict__ csw,
                                                   float* __restrict__ out) {
  __shared__ float B0[79 * 32], B1[79 * 32], B2[79 * 32];
  __shared__ float sacc[79 * 3];
  __shared__ float sW[576];
  int b = blockIdx.x, t = threadIdx.x;
  for (int i = t; i < 576; i += 256) sW[i] = W[i];
  for (int i = t; i < 2528; i += 256) {
    int r = i >> 5, f = i & 31;
    B0[i] = in[((size_t)r * 16 + b) * 32 + f];
  }
  __syncthreads();
  for (int i = t; i < 237; i += 256) {
    int r = i / 3, g = i % 3;
    float a = 0.f;
    for (int f = 0; f < 32; f++) a = fmaf(B0[r * 32 + f], sW[f * 3 + g], a);
    sacc[i] = a;
  }
  for (int i = t; i < 2528; i += 256) {
    int r = i >> 5, f = i & 31;
    float a = 0.f;
    for (int j = rowptr[r]; j < rowptr[r + 1]; j++) a = fmaf(csw[j], B0[csrc[j] * 32 + f], a);
    B1[i] = a;
  }
  __syncthreads();
  for (int i = t; i < 237; i += 256) {
    int r = i / 3, g = i % 3;
    float a = sacc[i];
    for (int f = 0; f < 32; f++) a = fmaf(B1[r * 32 + f], sW[96 + f * 3 + g], a);
    sacc[i] = a;
  }
  for (int i = t; i < 2528; i += 256) {
    int r = i >> 5, f = i & 31;
    float a = 0.f;
    for (int j = rowptr[r]; j < rowptr[r + 1]; j++) a = fmaf(csw[j], B1[csrc[j] * 32 + f], a);
    B2[i] = 2.f * a - B0[i];
  }
  __syncthreads();
  for (int i = t; i < 237; i += 256) {
    int r = i / 3, g = i % 3;
    float a = sacc[i];
    for (int f = 0; f < 32; f++) a = fmaf(B2[r * 32 + f], sW[192 + f * 3 + g], a);
    sacc[i] = a;
  }
  __syncthreads();
  for (int i = t; i < 2528; i += 256) {
    int r = i >> 5, f = i & 31;
    float a = 0.f;
    for (int j = rowptr[r]; j < rowptr[r + 1]; j++) a = fmaf(csw[j], B2[csrc[j] * 32 + f], a);
    B0[i] = 2.f * a - B1[i];
  }
  __syncthreads();
  for (int i = t; i < 237; i += 256) {
    int r = i / 3, g = i % 3;
    float a = sacc[i];
    for (int f = 0; f < 32; f++) a = fmaf(B0[r * 32 + f], sW[288 + f * 3 + g], a);
    sacc[i] = a;
  }
  __syncthreads();
  for (int i = t; i < 2528; i += 256) {
    int r = i >> 5, f = i & 31;
    float a = 0.f;
    for (int j = rowptr[r]; j < rowptr[r + 1]; j++) a = fmaf(csw[j], B0[csrc[j] * 32 + f], a);
    B1[i] = 2.f * a - B2[i];
  }
  __syncthreads();
  for (int i = t; i < 237; i += 256) {
    int r = i / 3, g = i % 3;
    float a = sacc[i];
    for (int f = 0; f < 32; f++) a = fmaf(B1[r * 32 + f], sW[384 + f * 3 + g], a);
    sacc[i] = a;
  }
  __syncthreads();
  for (int i = t; i < 2528; i += 256) {
    int r = i >> 5, f = i & 31;
    float a = 0.f;
    for (int j = rowptr[r]; j < rowptr[r + 1]; j++) a = fmaf(csw[j], B1[csrc[j] * 32 + f], a);
    B2[i] = 2.f * a - B0[i];
  }
  __syncthreads();
  for (int i = t; i < 237; i += 256) {
    int r = i / 3, g = i % 3;
    float a = sacc[i];
    for (int f = 0; f < 32; f++) a = fmaf(B2[r * 32 + f], sW[480 + f * 3 + g], a);
    out[((size_t)b * 20000 + r) * 3 + g] = a;
  }
}

// upsample in L layout (relu fused on input)
template <int F>
__global__ __launch_bounds__(WG) void k_us(const float* __restrict__ in,
                                           float* __restrict__ out,
                                           const int* __restrict__ uidx,
                                           const float* __restrict__ uw, int Nf) {
  int i = blockIdx.x * WG + threadIdx.x;
  int total = Nf * NB * F;
  if (i >= total) return;
  int pos = i % (NB * F);
  int r = i / (NB * F);
  float acc = 0.f;
#pragma unroll
  for (int k = 0; k < 3; k++) {
    float v = in[(size_t)uidx[r * 3 + k] * NB * F + pos];
    acc = fmaf(uw[r * 3 + k], fmaxf(v, 0.f), acc);
  }
  out[i] = acc;
}

// ---------------- latent kernels (L layout h: (79,16,64)) ----------------

__global__ __launch_bounds__(64) void k_latent(const float* __restrict__ h,
                                               const float* __restrict__ muW,
                                               const float* __restrict__ muB,
                                               const float* __restrict__ lvW,
                                               const float* __restrict__ lvB,
                                               const float* __restrict__ eps,
                                               const float* __restrict__ label,
                                               float* __restrict__ mu_out,
                                               float* __restrict__ lv_out,
                                               float* __restrict__ hcat) {
  int b = blockIdx.x / 64;
  int g = blockIdx.x % 64;
  int l = threadIdx.x;
  float am = 0.f, al = 0.f;
  for (int i = l; i < 5056; i += 64) {
    int n = i >> 6, f = i & 63;
    float hv = h[(size_t)(n * 16 + b) * 64 + f];
    am = fmaf(hv, muW[(size_t)i * 64 + g], am);
    al = fmaf(hv, lvW[(size_t)i * 64 + g], al);
  }
  for (int off = 32; off > 0; off >>= 1) {
    am += __shfl_down(am, off, 64);
    al += __shfl_down(al, off, 64);
  }
  if (l == 0) {
    am += muB[g];
    al += lvB[g];
    mu_out[b * 64 + g] = am;
    lv_out[b * 64 + g] = al;
    hcat[b * 66 + g] = fmaf(eps[b * 64 + g], expf(0.5f * al), am);
    if (g < 2) hcat[b * 66 + 64 + g] = label[b * 2 + g];
  }
}

__global__ __launch_bounds__(WG) void k_declin(const float* __restrict__ hcat,
                                               const float* __restrict__ W,
                                               const float* __restrict__ bias,
                                               float* __restrict__ out) {
  int idx = blockIdx.x * WG + threadIdx.x;
  if (idx >= NB * 5056) return;
  int b = idx / 5056, j = idx % 5056;
  int n = j >> 6, f = j & 63;
  float acc = bias[j];
  const float* hc = hcat + b * 66;
#pragma unroll
  for (int i = 0; i < 66; i++) acc = fmaf(hc[i], W[(size_t)i * 5056 + j], acc);
  out[(size_t)(n * 16 + b) * 64 + f] = fmaxf(acc, 0.f);
}

// ---------------- host orchestration ----------------

static inline dim3 grid1(long n) { return dim3((unsigned)((n + WG - 1) / WG)); }

template <int F, int G>
static void run_cheb(float* in, float* out, float* A, float* B,
                     const float* W, const float* bias, int N, int Nout,
                     const int* ds_idx, int relu_last,
                     const int* rowptr, const int* csrc, const float* csw,
                     hipStream_t st) {
  int orows = NB * Nout;
  dim3 gP((unsigned)((N + 3) / 4));
  int relu2 = ds_idx ? 1 : relu_last;
  if constexpr (F == 3) {
    constexpr int RPB = (WG / (G / 4)) * 4;
    dim3 gG((unsigned)((orows + RPB - 1) / RPB));
    k_propw3<<<gP, WG, 0, st>>>(in, A, nullptr, 1.f, rowptr, csrc, csw, N);
    k_propw3<<<gP, WG, 0, st>>>(A, B, in, 2.f, rowptr, csrc, csw, N);
    Ptr3 p1{{in, A, B}};
    k_gemm3<F, G><<<gG, WG, 0, st>>>(p1, W, bias, out, orows, ds_idx, 0, 0);
    k_propw3<<<gP, WG, 0, st>>>(B, in, A, 2.f, rowptr, csrc, csw, N);
    k_propw3<<<gP, WG, 0, st>>>(in, A, B, 2.f, rowptr, csrc, csw, N);
    k_propw3<<<gP, WG, 0, st>>>(A, B, in, 2.f, rowptr, csrc, csw, N);
    Ptr3 p2{{in, A, B}};
    k_gemm3<F, G><<<gG, WG, 0, st>>>(p2, W + 3 * F * G, nullptr, out, orows, ds_idx, 1, relu2);
  } else if constexpr (G == 32) {
    constexpr int BS = (F == 64) ? 128 : 256;
    dim3 gG((unsigned)((orows + BS - 1) / BS));
    k_propw<F><<<gP, WG, 0, st>>>(in, A, nullptr, 1.f, rowptr, csrc, csw, N);
    k_propw<F><<<gP, WG, 0, st>>>(A, B, in, 2.f, rowptr, csrc, csw, N);
    Ptr3 p1{{in, A, B}};
    k_gemm3s<F, BS><<<gG, BS, 0, st>>>(p1, W, bias, out, orows, ds_idx, 0, 0);
    k_propw<F><<<gP, WG, 0, st>>>(B, in, A, 2.f, rowptr, csrc, csw, N);
    k_propw<F><<<gP, WG, 0, st>>>(in, A, B, 2.f, rowptr, csrc, csw, N);
    k_propw<F><<<gP, WG, 0, st>>>(A, B, in, 2.f, rowptr, csrc, csw, N);
    Ptr3 p2{{in, A, B}};
    k_gemm3s<F, BS><<<gG, BS, 0, st>>>(p2, W + 3 * F * G, nullptr, out, orows, ds_idx, 1, relu2);
  } else {
    constexpr int RPB = (WG / (G / 4)) * 4;
    dim3 gG((unsigned)((orows + RPB - 1) / RPB));
    k_propw<F><<<gP, WG, 0, st>>>(in, A, nullptr, 1.f, rowptr, csrc, csw, N);
    k_propw<F><<<gP, WG, 0, st>>>(A, B, in, 2.f, rowptr, csrc, csw, N);
    Ptr3 p1{{in, A, B}};
    k_gemm3<F, G><<<gG, WG, 0, st>>>(p1, W, bias, out, orows, ds_idx, 0, 0);
    k_propw<F><<<gP, WG, 0, st>>>(B, in, A, 2.f, rowptr, csrc, csw, N);
    k_propw<F><<<gP, WG, 0, st>>>(in, A, B, 2.f, rowptr, csrc, csw, N);
    k_propw<F><<<gP, WG, 0, st>>>(A, B, in, 2.f, rowptr, csrc, csw, N);
    Ptr3 p2{{in, A, B}};
    k_gemm3<F, G><<<gG, WG, 0, st>>>(p2, W + 3 * F * G, nullptr, out, orows, ds_idx, 1, relu2);
  }
}

extern "C" void kernel_launch(void* const* d_in, const int* in_sizes, int n_in,
                              void* d_out, int out_size, void* d_ws, size_t ws_size,
                              hipStream_t stream) {
  const float* x = (const float*)d_in[0];
  const float* label = (const float*)d_in[1];
  IP5 ep;
  for (int l = 0; l < 5; l++) ep.e[l] = (const int*)d_in[2 + l];
  const int* ds_idx[4];
  const int* us_idx[4];
  const float* us_w[4];
  for (int i = 0; i < 4; i++) {
    ds_idx[i] = (const int*)d_in[7 + 3 * i];
    us_idx[i] = (const int*)d_in[8 + 3 * i];
    us_w[i] = (const float*)d_in[9 + 3 * i];
  }
  const float* enc_w[4];
  const float* enc_b[4];
  for (int i = 0; i < 4; i++) {
    enc_w[i] = (const float*)d_in[19 + 2 * i];
    enc_b[i] = (const float*)d_in[20 + 2 * i];
  }
  const float* dec_w[5];
  for (int i = 0; i < 5; i++) dec_w[i] = (const float*)d_in[27 + i];
  const float* dec_b[4];
  for (int i = 0; i < 4; i++) dec_b[i] = (const float*)d_in[32 + i];
  const float* mu_w = (const float*)d_in[36];
  const float* mu_b = (const float*)d_in[37];
  const float* lv_w = (const float*)d_in[38];
  const float* lv_b = (const float*)d_in[39];
  const float* dl_w = (const float*)d_in[40];
  const float* dl_b = (const float*)d_in[41];

  float* wsf = (float*)d_ws;
  size_t off = 0;
  auto carve = [&](size_t n) -> float* {
    float* p = wsf + off;
    off += (n + 63) & ~(size_t)63;
    return p;
  };
  const size_t SLOT = 10240000;  // 16*20000*32 floats
  float* s0 = carve(SLOT);
  float* s1 = carve(SLOT);
  float* s2 = carve(SLOT);
  float* s3 = carve(SLOT);
  float* sxl = carve(960000);
  int* deg_all = (int*)carve(26642 + 46563);
  int* deg_src_all = deg_all;
  int* deg_tgt_all = deg_all + 26642;
  int* rowptr_all = (int*)carve(46568);
  int* cursor_all = (int*)carve(46563);
  int* csrc_all = (int*)carve(159852);
  float* csw_all = carve(159852);
  float* eps = carve(1024);
  float* hcat = carve(1056);

  static const int ROFF[5] = {0, 20001, 25002, 26253, 26567};
  static const int EOFF[5] = {0, 120000, 150000, 157500, 159378};
  auto RP = [&](int l) { return rowptr_all + ROFF[l]; };
  auto CS = [&](int l) { return csrc_all + EOFF[l]; };
  auto CW = [&](int l) { return csw_all + EOFF[l]; };

  // ---- setup: 4 launches ----
  k_zero_i<<<grid1(26642 + 46563), WG, 0, stream>>>(deg_all, 26642 + 46563);
  k_hist_all<<<grid1(159852), WG, 0, stream>>>(ep, deg_src_all, deg_tgt_all);
  k_scan_all<<<5, WG, 0, stream>>>(deg_tgt_all, rowptr_all, cursor_all);
  k_fill_all<<<625 + 4 + 3750, WG, 0, stream>>>(ep, deg_src_all, cursor_all, csrc_all,
                                                csw_all, eps, x, sxl);

  float* mu_out = (float*)d_out + 960000;
  float* lv_out = (float*)d_out + 961024;

  // ---- encoder (ds+relu fused into gemm via row indirection) ----
  run_cheb<3, 32>(sxl, s1, s2, s3, enc_w[0], enc_b[0], 20000, 5000, ds_idx[0], 0,
                  RP(0), CS(0), CW(0), stream);
  run_cheb<32, 32>(s1, s0, s2, s3, enc_w[1], enc_b[1], 5000, 1250, ds_idx[1], 0,
                   RP(1), CS(1), CW(1), stream);
  run_cheb<32, 64>(s0, s1, s2, s3, enc_w[2], enc_b[2], 1250, 313, ds_idx[2], 0,
                   RP(2), CS(2), CW(2), stream);
  run_cheb<64, 64>(s1, s0, s2, s3, enc_w[3], enc_b[3], 313, 79, ds_idx[3], 0,
                   RP(3), CS(3), CW(3), stream);

  // ---- latent ----
  k_latent<<<1024, 64, 0, stream>>>(s0, mu_w, mu_b, lv_w, lv_b, eps, label, mu_out, lv_out, hcat);
  k_declin<<<grid1(NB * 5056), WG, 0, stream>>>(hcat, dl_w, dl_b, s0);

  // ---- decoder ----
  k_us<64><<<grid1((long)313 * NB * 64), WG, 0, stream>>>(s0, s1, us_idx[3], us_w[3], 313);
  run_cheb<64, 64>(s1, s0, s2, s3, dec_w[0], dec_b[0], 313, 313, nullptr, 0,
                   RP(3), CS(3), CW(3), stream);
  k_us<64><<<grid1((long)1250 * NB * 64), WG, 0, stream>>>(s0, s1, us_idx[2], us_w[2], 1250);
  run_cheb<64, 64>(s1, s0, s2, s3, dec_w[1], dec_b[1], 1250, 1250, nullptr, 0,
                   RP(2), CS(2), CW(2), stream);
  k_us<64><<<grid1((long)5000 * NB * 64), WG, 0, stream>>>(s0, s1, us_idx[1], us_w[1], 5000);
  run_cheb<64, 32>(s1, s0, s2, s3, dec_w[2], dec_b[2], 5000, 5000, nullptr, 0,
                   RP(1), CS(1), CW(1), stream);
  k_us<32><<<grid1((long)20000 * NB * 32), WG, 0, stream>>>(s0, s1, us_idx[0], us_w[0], 20000);

  // ---- decoder level 0 (manual): pass2 fused with relu + level-4 shortcut ----
  {
    const int N = 20000;
    int rows = NB * N;  // 320000, multiple of 256
    dim3 gP((unsigned)((N + 3) / 4));
    dim3 gG((unsigned)(rows / 256));
    k_propw<32><<<gP, WG, 0, stream>>>(s1, s2, nullptr, 1.f, RP(0), CS(0), CW(0), N);  // T1
    k_propw<32><<<gP, WG, 0, stream>>>(s2, s3, s1, 2.f, RP(0), CS(0), CW(0), N);       // T2
    Ptr3 p1{{s1, s2, s3}};
    k_gemm3s<32, 256><<<gG, 256, 0, stream>>>(p1, dec_w[3], dec_b[3], s0, rows, nullptr, 0, 0);
    k_propw<32><<<gP, WG, 0, stream>>>(s3, s1, s2, 2.f, RP(0), CS(0), CW(0), N);       // T3
    k_propw<32><<<gP, WG, 0, stream>>>(s1, s2, s3, 2.f, RP(0), CS(0), CW(0), N);       // T4
    k_propw<32><<<gP, WG, 0, stream>>>(s2, s3, s1, 2.f, RP(0), CS(0), CW(0), N);       // T5
    Ptr3 p2{{s1, s2, s3}};
    k_gemm3s_final<<<gG, 256, 0, stream>>>(p2, dec_w[3] + 3 * 32 * 32, dec_w[4], s0,
                                           (float*)d_out, rows);
  }

  // ---- exact 79-node fixup ----
  k_final_fix<<<16, 256, 0, stream>>>(s0, dec_w[4], RP(4), CS(4), CW(4), (float*)d_out);
}

// Round 11
// 1199.533 us; speedup vs baseline: 1.3388x; 1.3388x over previous
//
#include <hip/hip_runtime.h>
#include <cstdint>
#include <cstddef>

#define WG 256
#define NB 16  // batch

// Layout "L": arr[(n*16 + b)*F + f]  — node-major, batch, feature.
// Cheb layers run in the MONOMIAL basis: out = sum_j (S^j X) @ C_j where
// C_j are precomputed combos of the Chebyshev weights (k_combine). Props are
// pure gathers Y_{j+1} = S·Y_j (no subtract term).

struct IP5 { const int* e[5]; };
struct Ptr3 { const float* p[3]; };
struct WComb { const float* w[8]; float* c[8]; };

static __device__ __forceinline__ void fma4(float4& a, float s, const float4& b) {
  a.x = fmaf(s, b.x, a.x); a.y = fmaf(s, b.y, a.y);
  a.z = fmaf(s, b.z, a.z); a.w = fmaf(s, b.w, a.w);
}

// ---------------- fused setup kernels ----------------

__global__ void k_zero_i(int* __restrict__ p, int n) {
  int i = blockIdx.x * WG + threadIdx.x;
  if (i < n) p[i] = 0;
}

__global__ void k_hist_all(IP5 ep, int* __restrict__ dsrc, int* __restrict__ dtgt) {
  int i = blockIdx.x * WG + threadIdx.x;
  if (i >= 159852) return;
  int l, eo, ee, no, co;
  if (i < 120000)      { l = 0; eo = 0;      ee = 120000; no = 0;     co = 0; }
  else if (i < 150000) { l = 1; eo = 120000; ee = 30000;  no = 20000; co = 20000; }
  else if (i < 157500) { l = 2; eo = 150000; ee = 7500;   no = 25000; co = 25000; }
  else if (i < 159378) { l = 3; eo = 157500; ee = 1878;   no = 26250; co = 26250; }
  else                 { l = 4; eo = 159378; ee = 474;    no = 26563; co = 26563; }
  int e = i - eo;
  const int* E = ep.e[l];
  atomicAdd(&dsrc[no + E[e]], 1);
  atomicAdd(&dtgt[co + E[ee + e]], 1);
}

__global__ void k_scan_all(const int* __restrict__ deg_all, int* __restrict__ rowptr_all,
                           int* __restrict__ cursor_all) {
  static const int Ns[5] = {20000, 5000, 1250, 313, 20000};
  static const int CO[5] = {0, 20000, 25000, 26250, 26563};
  static const int RO[5] = {0, 20001, 25002, 26253, 26567};
  __shared__ int s[WG];
  int l = blockIdx.x;
  int N = Ns[l];
  const int* deg = deg_all + CO[l];
  int* rowptr = rowptr_all + RO[l];
  int* cursor = cursor_all + CO[l];
  int t = threadIdx.x;
  int chunk = (N + WG - 1) / WG;
  int a = t * chunk;
  int b = min(N, a + chunk);
  int sum = 0;
  for (int i = a; i < b; i++) sum += deg[i];
  s[t] = sum;
  __syncthreads();
  for (int off = 1; off < WG; off <<= 1) {
    int v = (t >= off) ? s[t - off] : 0;
    __syncthreads();
    s[t] += v;
    __syncthreads();
  }
  int run = (t == 0) ? 0 : s[t - 1];
  for (int i = a; i < b; i++) {
    rowptr[i] = run;
    cursor[i] = run;
    run += deg[i];
  }
  if (t == 0) rowptr[N] = s[WG - 1];
}

// monomial-basis weight combos for all 8 cheb layers
__global__ void k_combine(WComb wc) {
  static const int M[8] = {96, 1024, 2048, 4096, 4096, 4096, 2048, 1024};
  static const int OFF[8] = {0, 96, 1120, 3168, 7264, 11360, 15456, 17504};
  int i = blockIdx.x * WG + threadIdx.x;
  if (i >= 18528) return;
  int l = 0;
  while (l < 7 && i >= OFF[l + 1]) l++;
  int e = i - OFF[l], m = M[l];
  const float* w = wc.w[l];
  float* c = wc.c[l];
  float w0 = w[e], w1 = w[m + e], w2 = w[2 * m + e];
  float w3 = w[3 * m + e], w4 = w[4 * m + e], w5 = w[5 * m + e];
  c[e]         = w0 - w2 + w4;
  c[m + e]     = w1 - 3.f * w3 + 5.f * w5;
  c[2 * m + e] = 2.f * w2 - 8.f * w4;
  c[3 * m + e] = 4.f * w3 - 20.f * w5;
  c[4 * m + e] = 8.f * w4;
  c[5 * m + e] = 16.f * w5;
}

// ---------------- threefry eps (verified vs harness JAX ref) ----------------

static __device__ __forceinline__ float erfinv_f(float x) {
  float w = -log1pf(-x * x);
  float p;
  if (w < 5.0f) {
    w -= 2.5f;
    p = 2.81022636e-08f;
    p = fmaf(p, w, 3.43273939e-07f);
    p = fmaf(p, w, -3.5233877e-06f);
    p = fmaf(p, w, -4.39150654e-06f);
    p = fmaf(p, w, 0.00021858087f);
    p = fmaf(p, w, -0.00125372503f);
    p = fmaf(p, w, -0.00417768164f);
    p = fmaf(p, w, 0.246640727f);
    p = fmaf(p, w, 1.50140941f);
  } else {
    w = sqrtf(w) - 3.0f;
    p = -0.000200214257f;
    p = fmaf(p, w, 0.000100950558f);
    p = fmaf(p, w, 0.00134934322f);
    p = fmaf(p, w, -0.00367342844f);
    p = fmaf(p, w, 0.00573950773f);
    p = fmaf(p, w, -0.0076224613f);
    p = fmaf(p, w, 0.00943887047f);
    p = fmaf(p, w, 1.00167406f);
    p = fmaf(p, w, 2.83297682f);
  }
  return p * x;
}

static __device__ __forceinline__ float bits_to_normal(unsigned b) {
  float f = __uint_as_float((b >> 9) | 0x3f800000u) - 1.0f;
  const float lo = -0.99999994f;
  float u = f * (1.0f - lo) + lo;
  u = fmaxf(u, lo);
  return 1.41421356f * erfinv_f(u);
}

static __device__ __forceinline__ float eps_val(int i) {
  unsigned x0 = 0u, x1 = (unsigned)i;
  unsigned ks[3] = {0u, 42u, 0u ^ 42u ^ 0x1BD11BDAu};
  x0 += ks[0];
  x1 += ks[1];
  const int R[2][4] = {{13, 15, 26, 6}, {17, 29, 16, 24}};
#pragma unroll
  for (int it = 0; it < 5; it++) {
#pragma unroll
    for (int j = 0; j < 4; j++) {
      x0 += x1;
      int r = R[it & 1][j];
      x1 = (x1 << r) | (x1 >> (32 - r));
      x1 ^= x0;
    }
    x0 += ks[(it + 1) % 3];
    x1 += ks[(it + 2) % 3] + (unsigned)(it + 1);
  }
  return bits_to_normal(x0 ^ x1);
}

__global__ void k_fill_all(IP5 ep, const int* __restrict__ dsrc, int* __restrict__ cursor,
                           int* __restrict__ csrc, float* __restrict__ csw,
                           float* __restrict__ eps, const float* __restrict__ x,
                           float* __restrict__ sxl) {
  int blk = blockIdx.x;
  if (blk < 625) {
    int i = blk * WG + threadIdx.x;
    if (i >= 159852) return;
    int l, eo, ee, no, co, eb;
    if (i < 120000)      { l = 0; eo = 0;      ee = 120000; no = 0;     co = 0;     eb = 0; }
    else if (i < 150000) { l = 1; eo = 120000; ee = 30000;  no = 20000; co = 20000; eb = 120000; }
    else if (i < 157500) { l = 2; eo = 150000; ee = 7500;   no = 25000; co = 25000; eb = 150000; }
    else if (i < 159378) { l = 3; eo = 157500; ee = 1878;   no = 26250; co = 26250; eb = 157500; }
    else                 { l = 4; eo = 159378; ee = 474;    no = 26563; co = 26563; eb = 159378; }
    int e = i - eo;
    const int* E = ep.e[l];
    int s = E[e], t = E[ee + e];
    float da = (float)dsrc[no + s], db = (float)dsrc[no + t];
    float wa = (da > 0.f) ? (1.0f / sqrtf(da)) : 0.f;
    float wb = (db > 0.f) ? (1.0f / sqrtf(db)) : 0.f;
    int pos = atomicAdd(&cursor[co + t], 1);
    csrc[eb + pos] = s;
    csw[eb + pos] = wa * wb;
  } else if (blk < 629) {
    int j = (blk - 625) * WG + threadIdx.x;
    if (j < 1024) eps[j] = eps_val(j);
  } else {
    int j = (blk - 629) * WG + threadIdx.x;
    if (j >= NB * 20000 * 3) return;
    int f = j % 3;
    int b = (j / 3) % NB;
    int n = j / 48;
    sxl[j] = x[((size_t)b * 20000 + n) * 3 + f];
  }
}

// ---------------- wave-per-node propagation: out = S * in (4-edge unrolled) ----------------

#define RFL_I(v) __builtin_amdgcn_readfirstlane(v)
#define RFL_F(v) __int_as_float(__builtin_amdgcn_readfirstlane(__float_as_int(v)))

template <int F>
__global__ __launch_bounds__(WG) void k_propw(const float* __restrict__ in,
                                              float* __restrict__ out,
                                              const int* __restrict__ rowptr,
                                              const int* __restrict__ csrc,
                                              const float* __restrict__ csw, int N) {
  constexpr int C4 = F / 16;
  int node = blockIdx.x * 4 + (threadIdx.x >> 6);
  if (node >= N) return;
  int lane = threadIdx.x & 63;
  const float4* in4 = (const float4*)in;
  float4 acc[C4];
#pragma unroll
  for (int u = 0; u < C4; u++) acc[u] = make_float4(0.f, 0.f, 0.f, 0.f);
  int beg = rowptr[node], end = rowptr[node + 1];
  int j = beg;
  for (; j + 3 < end; j += 4) {
    int s0 = RFL_I(csrc[j]);
    int s1 = RFL_I(csrc[j + 1]);
    int s2 = RFL_I(csrc[j + 2]);
    int s3 = RFL_I(csrc[j + 3]);
    float w0 = RFL_F(csw[j]);
    float w1 = RFL_F(csw[j + 1]);
    float w2 = RFL_F(csw[j + 2]);
    float w3 = RFL_F(csw[j + 3]);
    const float4* p0 = in4 + (size_t)s0 * (4 * F) + lane;
    const float4* p1 = in4 + (size_t)s1 * (4 * F) + lane;
    const float4* p2 = in4 + (size_t)s2 * (4 * F) + lane;
    const float4* p3 = in4 + (size_t)s3 * (4 * F) + lane;
    float4 v0[C4], v1[C4], v2[C4], v3[C4];
#pragma unroll
    for (int u = 0; u < C4; u++) v0[u] = p0[u * 64];
#pragma unroll
    for (int u = 0; u < C4; u++) v1[u] = p1[u * 64];
#pragma unroll
    for (int u = 0; u < C4; u++) v2[u] = p2[u * 64];
#pragma unroll
    for (int u = 0; u < C4; u++) v3[u] = p3[u * 64];
#pragma unroll
    for (int u = 0; u < C4; u++) {
      fma4(acc[u], w0, v0[u]);
      fma4(acc[u], w1, v1[u]);
      fma4(acc[u], w2, v2[u]);
      fma4(acc[u], w3, v3[u]);
    }
  }
  for (; j < end; j++) {
    int s0 = RFL_I(csrc[j]);
    float w0 = RFL_F(csw[j]);
    const float4* p0 = in4 + (size_t)s0 * (4 * F) + lane;
#pragma unroll
    for (int u = 0; u < C4; u++) {
      float4 v0 = p0[u * 64];
      fma4(acc[u], w0, v0);
    }
  }
  float4* o4 = (float4*)out + (size_t)node * (4 * F) + lane;
#pragma unroll
  for (int u = 0; u < C4; u++) o4[u * 64] = acc[u];
}

// F=3 variant
__global__ __launch_bounds__(WG) void k_propw3(const float* __restrict__ in,
                                               float* __restrict__ out,
                                               const int* __restrict__ rowptr,
                                               const int* __restrict__ csrc,
                                               const float* __restrict__ csw, int N) {
  int node = blockIdx.x * 4 + (threadIdx.x >> 6);
  if (node >= N) return;
  int lane = threadIdx.x & 63;
  if (lane >= 48) return;
  float acc = 0.f;
  int beg = rowptr[node], end = rowptr[node + 1];
  for (int j = beg; j < end; j++) {
    int s = RFL_I(csrc[j]);
    float w = RFL_F(csw[j]);
    acc = fmaf(w, in[(size_t)s * 48 + lane], acc);
  }
  out[(size_t)node * 48 + lane] = acc;
}

// ---------------- fused 3-term GEMM, 4 rows x 4 cols per thread ----------------

template <int F, int G>
__global__ __launch_bounds__(WG) void k_gemm3(Ptr3 txs, const float* __restrict__ W,
                                              const float* __restrict__ bias,
                                              float* __restrict__ out, int rows,
                                              const int* __restrict__ idx,
                                              int accum, int relu) {
  constexpr int CG = G / 4;
  constexpr int RT = WG / CG;
  constexpr int RPB = RT * 4;
  __shared__ float sW[3 * F * G];
  for (int i = threadIdx.x; i < 3 * F * G; i += WG) sW[i] = W[i];
  __syncthreads();
  int cg = threadIdx.x % CG;
  int rt = threadIdx.x / CG;
  int row0 = blockIdx.x * RPB + rt * 4;
  if (row0 >= rows) return;
  size_t src0 = row0;
  if (idx) {
    int node = row0 >> 4, b = row0 & 15;
    src0 = (size_t)idx[node] * 16 + b;
  }
  float* o = out + (size_t)row0 * G + cg * 4;
  float4 acc[4];
  if (accum) {
#pragma unroll
    for (int r = 0; r < 4; r++) acc[r] = *(const float4*)(o + (size_t)r * G);
  } else if (bias) {
    float4 bv = *(const float4*)(bias + cg * 4);
#pragma unroll
    for (int r = 0; r < 4; r++) acc[r] = bv;
  } else {
#pragma unroll
    for (int r = 0; r < 4; r++) acc[r] = make_float4(0.f, 0.f, 0.f, 0.f);
  }
#pragma unroll
  for (int kk = 0; kk < 3; kk++) {
    const float* tb = txs.p[kk] + src0 * F;
    const float* w = sW + kk * F * G + cg * 4;
    if constexpr (F == 3) {
      float4 w0 = *(const float4*)(w + 0 * G);
      float4 w1 = *(const float4*)(w + 1 * G);
      float4 w2 = *(const float4*)(w + 2 * G);
#pragma unroll
      for (int r = 0; r < 4; r++) {
        float x0 = tb[r * 3 + 0], x1 = tb[r * 3 + 1], x2 = tb[r * 3 + 2];
        fma4(acc[r], x0, w0);
        fma4(acc[r], x1, w1);
        fma4(acc[r], x2, w2);
      }
    } else {
#pragma unroll
      for (int fg = 0; fg < F / 4; fg++) {
        float4 xv[4];
#pragma unroll
        for (int r = 0; r < 4; r++) xv[r] = *(const float4*)(tb + (size_t)r * F + 4 * fg);
        float4 w0 = *(const float4*)(w + (4 * fg + 0) * G);
        float4 w1 = *(const float4*)(w + (4 * fg + 1) * G);
        float4 w2 = *(const float4*)(w + (4 * fg + 2) * G);
        float4 w3 = *(const float4*)(w + (4 * fg + 3) * G);
#pragma unroll
        for (int r = 0; r < 4; r++) {
          fma4(acc[r], xv[r].x, w0);
          fma4(acc[r], xv[r].y, w1);
          fma4(acc[r], xv[r].z, w2);
          fma4(acc[r], xv[r].w, w3);
        }
      }
    }
  }
  if (relu) {
#pragma unroll
    for (int r = 0; r < 4; r++) {
      acc[r].x = fmaxf(acc[r].x, 0.f); acc[r].y = fmaxf(acc[r].y, 0.f);
      acc[r].z = fmaxf(acc[r].z, 0.f); acc[r].w = fmaxf(acc[r].w, 0.f);
    }
  }
#pragma unroll
  for (int r = 0; r < 4; r++) *(float4*)(o + (size_t)r * G) = acc[r];
}

// ---- decoder level-0 gemm pass 2 fused with relu + level-4 shortcut ----
// F=32, G=32, R=4 tiling. rows % 128 == 0. W = monomial combos C3..C5;
// W4 = raw dec_w4 (shortcut combo W0-W2+W4 computed here, unchanged).
__global__ __launch_bounds__(WG) void k_gemm3_final(Ptr3 txs, const float* __restrict__ W,
                                                    const float* __restrict__ W4,
                                                    float* __restrict__ out,
                                                    float* __restrict__ dout, int rows) {
  constexpr int F = 32, G = 32;
  constexpr int CG = 8, RPB = 128;
  __shared__ float sW[3 * F * G];
  __shared__ float sWc[96];
  for (int i = threadIdx.x; i < 3 * F * G; i += WG) sW[i] = W[i];
  if (threadIdx.x < 96)
    sWc[threadIdx.x] = W4[threadIdx.x] - W4[192 + threadIdx.x] + W4[384 + threadIdx.x];
  __syncthreads();
  int cg = threadIdx.x % CG;
  int rt = threadIdx.x / CG;
  int row0 = blockIdx.x * RPB + rt * 4;
  float* o = out + (size_t)row0 * G + cg * 4;
  float4 acc[4];
#pragma unroll
  for (int r = 0; r < 4; r++) acc[r] = *(const float4*)(o + (size_t)r * G);
#pragma unroll
  for (int kk = 0; kk < 3; kk++) {
    const float* tb = txs.p[kk] + (size_t)row0 * F;
    const float* w = sW + kk * F * G + cg * 4;
#pragma unroll
    for (int fg = 0; fg < F / 4; fg++) {
      float4 xv[4];
#pragma unroll
      for (int r = 0; r < 4; r++) xv[r] = *(const float4*)(tb + (size_t)r * F + 4 * fg);
      float4 w0 = *(const float4*)(w + (4 * fg + 0) * G);
      float4 w1 = *(const float4*)(w + (4 * fg + 1) * G);
      float4 w2 = *(const float4*)(w + (4 * fg + 2) * G);
      float4 w3 = *(const float4*)(w + (4 * fg + 3) * G);
#pragma unroll
      for (int r = 0; r < 4; r++) {
        fma4(acc[r], xv[r].x, w0);
        fma4(acc[r], xv[r].y, w1);
        fma4(acc[r], xv[r].z, w2);
        fma4(acc[r], xv[r].w, w3);
      }
    }
  }
#pragma unroll
  for (int r = 0; r < 4; r++) {
    acc[r].x = fmaxf(acc[r].x, 0.f); acc[r].y = fmaxf(acc[r].y, 0.f);
    acc[r].z = fmaxf(acc[r].z, 0.f); acc[r].w = fmaxf(acc[r].w, 0.f);
  }
  // s0 slice for final_fix (nodes < 79); 4-row group never crosses a node
  if ((row0 >> 4) < 79) {
#pragma unroll
    for (int r = 0; r < 4; r++) *(float4*)(o + (size_t)r * G) = acc[r];
  }
  // level-4 shortcut: per-row 3-wide output, reduced across the 8 cg lanes
#pragma unroll
  for (int r = 0; r < 4; r++) {
    float av[4] = {acc[r].x, acc[r].y, acc[r].z, acc[r].w};
    float p0 = 0.f, p1 = 0.f, p2 = 0.f;
#pragma unroll
    for (int j = 0; j < 4; j++) {
      int f = cg * 4 + j;
      p0 = fmaf(av[j], sWc[f * 3 + 0], p0);
      p1 = fmaf(av[j], sWc[f * 3 + 1], p1);
      p2 = fmaf(av[j], sWc[f * 3 + 2], p2);
    }
#pragma unroll
    for (int m = 4; m >= 1; m >>= 1) {
      p0 += __shfl_xor(p0, m, 64);
      p1 += __shfl_xor(p1, m, 64);
      p2 += __shfl_xor(p2, m, 64);
    }
    if (cg == 0) {
      int row = row0 + r;
      int n = row >> 4, b = row & 15;
      float* od = dout + ((size_t)b * 20000 + n) * 3;
      od[0] = p0; od[1] = p1; od[2] = p2;
    }
  }
}

// exact K=6 Chebyshev fixup for the 79 real nodes (raw dec_w4, T-basis).
__global__ __launch_bounds__(256) void k_final_fix(const float* __restrict__ in,
                                                   const float* __restrict__ W,  // 6x32x3
                                                   const int* __restrict__ rowptr,
                                                   const int* __restrict__ csrc,
                                                   const float* __restrict__ csw,
                                                   float* __restrict__ out) {
  __shared__ float B0[79 * 32], B1[79 * 32], B2[79 * 32];
  __shared__ float sacc[79 * 3];
  __shared__ float sW[576];
  int b = blockIdx.x, t = threadIdx.x;
  for (int i = t; i < 576; i += 256) sW[i] = W[i];
  for (int i = t; i < 2528; i += 256) {
    int r = i >> 5, f = i & 31;
    B0[i] = in[((size_t)r * 16 + b) * 32 + f];
  }
  __syncthreads();
  for (int i = t; i < 237; i += 256) {
    int r = i / 3, g = i % 3;
    float a = 0.f;
    for (int f = 0; f < 32; f++) a = fmaf(B0[r * 32 + f], sW[f * 3 + g], a);
    sacc[i] = a;
  }
  for (int i = t; i < 2528; i += 256) {
    int r = i >> 5, f = i & 31;
    float a = 0.f;
    for (int j = rowptr[r]; j < rowptr[r + 1]; j++) a = fmaf(csw[j], B0[csrc[j] * 32 + f], a);
    B1[i] = a;
  }
  __syncthreads();
  for (int i = t; i < 237; i += 256) {
    int r = i / 3, g = i % 3;
    float a = sacc[i];
    for (int f = 0; f < 32; f++) a = fmaf(B1[r * 32 + f], sW[96 + f * 3 + g], a);
    sacc[i] = a;
  }
  for (int i = t; i < 2528; i += 256) {
    int r = i >> 5, f = i & 31;
    float a = 0.f;
    for (int j = rowptr[r]; j < rowptr[r + 1]; j++) a = fmaf(csw[j], B1[csrc[j] * 32 + f], a);
    B2[i] = 2.f * a - B0[i];
  }
  __syncthreads();
  for (int i = t; i < 237; i += 256) {
    int r = i / 3, g = i % 3;
    float a = sacc[i];
    for (int f = 0; f < 32; f++) a = fmaf(B2[r * 32 + f], sW[192 + f * 3 + g], a);
    sacc[i] = a;
  }
  __syncthreads();
  for (int i = t; i < 2528; i += 256) {
    int r = i >> 5, f = i & 31;
    float a = 0.f;
    for (int j = rowptr[r]; j < rowptr[r + 1]; j++) a = fmaf(csw[j], B2[csrc[j] * 32 + f], a);
    B0[i] = 2.f * a - B1[i];
  }
  __syncthreads();
  for (int i = t; i < 237; i += 256) {
    int r = i / 3, g = i % 3;
    float a = sacc[i];
    for (int f = 0; f < 32; f++) a = fmaf(B0[r * 32 + f], sW[288 + f * 3 + g], a);
    sacc[i] = a;
  }
  __syncthreads();
  for (int i = t; i < 2528; i += 256) {
    int r = i >> 5, f = i & 31;
    float a = 0.f;
    for (int j = rowptr[r]; j < rowptr[r + 1]; j++) a = fmaf(csw[j], B0[csrc[j] * 32 + f], a);
    B1[i] = 2.f * a - B2[i];
  }
  __syncthreads();
  for (int i = t; i < 237; i += 256) {
    int r = i / 3, g = i % 3;
    float a = sacc[i];
    for (int f = 0; f < 32; f++) a = fmaf(B1[r * 32 + f], sW[384 + f * 3 + g], a);
    sacc[i] = a;
  }
  __syncthreads();
  for (int i = t; i < 2528; i += 256) {
    int r = i >> 5, f = i & 31;
    float a = 0.f;
    for (int j = rowptr[r]; j < rowptr[r + 1]; j++) a = fmaf(csw[j], B1[csrc[j] * 32 + f], a);
    B2[i] = 2.f * a - B0[i];
  }
  __syncthreads();
  for (int i = t; i < 237; i += 256) {
    int r = i / 3, g = i % 3;
    float a = sacc[i];
    for (int f = 0; f < 32; f++) a = fmaf(B2[r * 32 + f], sW[480 + f * 3 + g], a);
    out[((size_t)b * 20000 + r) * 3 + g] = a;
  }
}

// upsample in L layout (relu fused on input)
template <int F>
__global__ __launch_bounds__(WG) void k_us(const float* __restrict__ in,
                                           float* __restrict__ out,
                                           const int* __restrict__ uidx,
                                           const float* __restrict__ uw, int Nf) {
  int i = blockIdx.x * WG + threadIdx.x;
  int total = Nf * NB * F;
  if (i >= total) return;
  int pos = i % (NB * F);
  int r = i / (NB * F);
  float acc = 0.f;
#pragma unroll
  for (int k = 0; k < 3; k++) {
    float v = in[(size_t)uidx[r * 3 + k] * NB * F + pos];
    acc = fmaf(uw[r * 3 + k], fmaxf(v, 0.f), acc);
  }
  out[i] = acc;
}

// ---------------- latent kernels (L layout h: (79,16,64)) ----------------

__global__ __launch_bounds__(64) void k_latent(const float* __restrict__ h,
                                               const float* __restrict__ muW,
                                               const float* __restrict__ muB,
                                               const float* __restrict__ lvW,
                                               const float* __restrict__ lvB,
                                               const float* __restrict__ eps,
                                               const float* __restrict__ label,
                                               float* __restrict__ mu_out,
                                               float* __restrict__ lv_out,
                                               float* __restrict__ hcat) {
  int b = blockIdx.x / 64;
  int g = blockIdx.x % 64;
  int l = threadIdx.x;
  float am = 0.f, al = 0.f;
  for (int i = l; i < 5056; i += 64) {
    int n = i >> 6, f = i & 63;
    float hv = h[(size_t)(n * 16 + b) * 64 + f];
    am = fmaf(hv, muW[(size_t)i * 64 + g], am);
    al = fmaf(hv, lvW[(size_t)i * 64 + g], al);
  }
  for (int off = 32; off > 0; off >>= 1) {
    am += __shfl_down(am, off, 64);
    al += __shfl_down(al, off, 64);
  }
  if (l == 0) {
    am += muB[g];
    al += lvB[g];
    mu_out[b * 64 + g] = am;
    lv_out[b * 64 + g] = al;
    hcat[b * 66 + g] = fmaf(eps[b * 64 + g], expf(0.5f * al), am);
    if (g < 2) hcat[b * 66 + 64 + g] = label[b * 2 + g];
  }
}

__global__ __launch_bounds__(WG) void k_declin(const float* __restrict__ hcat,
                                               const float* __restrict__ W,
                                               const float* __restrict__ bias,
                                               float* __restrict__ out) {
  int idx = blockIdx.x * WG + threadIdx.x;
  if (idx >= NB * 5056) return;
  int b = idx / 5056, j = idx % 5056;
  int n = j >> 6, f = j & 63;
  float acc = bias[j];
  const float* hc = hcat + b * 66;
#pragma unroll
  for (int i = 0; i < 66; i++) acc = fmaf(hc[i], W[(size_t)i * 5056 + j], acc);
  out[(size_t)(n * 16 + b) * 64 + f] = fmaxf(acc, 0.f);
}

// ---------------- host orchestration ----------------

static inline dim3 grid1(long n) { return dim3((unsigned)((n + WG - 1) / WG)); }

// Monomial-basis cheb layer: Y1..Y5 by pure props, 2 gemm passes with combos.
template <int F, int G>
static void run_cheb(float* in, float* out, float* A, float* B,
                     const float* C, const float* bias, int N, int Nout,
                     const int* ds_idx, int relu_last,
                     const int* rowptr, const int* csrc, const float* csw,
                     hipStream_t st) {
  int orows = NB * Nout;
  dim3 gP((unsigned)((N + 3) / 4));
  constexpr int RPB = (WG / (G / 4)) * 4;
  dim3 gG((unsigned)((orows + RPB - 1) / RPB));
  int relu2 = ds_idx ? 1 : relu_last;
  if constexpr (F == 3) {
    k_propw3<<<gP, WG, 0, st>>>(in, A, rowptr, csrc, csw, N);
    k_propw3<<<gP, WG, 0, st>>>(A, B, rowptr, csrc, csw, N);
    Ptr3 p1{{in, A, B}};
    k_gemm3<F, G><<<gG, WG, 0, st>>>(p1, C, bias, out, orows, ds_idx, 0, 0);
    k_propw3<<<gP, WG, 0, st>>>(B, in, rowptr, csrc, csw, N);
    k_propw3<<<gP, WG, 0, st>>>(in, A, rowptr, csrc, csw, N);
    k_propw3<<<gP, WG, 0, st>>>(A, B, rowptr, csrc, csw, N);
    Ptr3 p2{{in, A, B}};
    k_gemm3<F, G><<<gG, WG, 0, st>>>(p2, C + 3 * F * G, nullptr, out, orows, ds_idx, 1, relu2);
  } else {
    k_propw<F><<<gP, WG, 0, st>>>(in, A, rowptr, csrc, csw, N);       // Y1
    k_propw<F><<<gP, WG, 0, st>>>(A, B, rowptr, csrc, csw, N);        // Y2
    Ptr3 p1{{in, A, B}};
    k_gemm3<F, G><<<gG, WG, 0, st>>>(p1, C, bias, out, orows, ds_idx, 0, 0);
    k_propw<F><<<gP, WG, 0, st>>>(B, in, rowptr, csrc, csw, N);       // Y3
    k_propw<F><<<gP, WG, 0, st>>>(in, A, rowptr, csrc, csw, N);       // Y4
    k_propw<F><<<gP, WG, 0, st>>>(A, B, rowptr, csrc, csw, N);        // Y5
    Ptr3 p2{{in, A, B}};
    k_gemm3<F, G><<<gG, WG, 0, st>>>(p2, C + 3 * F * G, nullptr, out, orows, ds_idx, 1, relu2);
  }
}

extern "C" void kernel_launch(void* const* d_in, const int* in_sizes, int n_in,
                              void* d_out, int out_size, void* d_ws, size_t ws_size,
                              hipStream_t stream) {
  const float* x = (const float*)d_in[0];
  const float* label = (const float*)d_in[1];
  IP5 ep;
  for (int l = 0; l < 5; l++) ep.e[l] = (const int*)d_in[2 + l];
  const int* ds_idx[4];
  const int* us_idx[4];
  const float* us_w[4];
  for (int i = 0; i < 4; i++) {
    ds_idx[i] = (const int*)d_in[7 + 3 * i];
    us_idx[i] = (const int*)d_in[8 + 3 * i];
    us_w[i] = (const float*)d_in[9 + 3 * i];
  }
  const float* enc_w[4];
  const float* enc_b[4];
  for (int i = 0; i < 4; i++) {
    enc_w[i] = (const float*)d_in[19 + 2 * i];
    enc_b[i] = (const float*)d_in[20 + 2 * i];
  }
  const float* dec_w[5];
  for (int i = 0; i < 5; i++) dec_w[i] = (const float*)d_in[27 + i];
  const float* dec_b[4];
  for (int i = 0; i < 4; i++) dec_b[i] = (const float*)d_in[32 + i];
  const float* mu_w = (const float*)d_in[36];
  const float* mu_b = (const float*)d_in[37];
  const float* lv_w = (const float*)d_in[38];
  const float* lv_b = (const float*)d_in[39];
  const float* dl_w = (const float*)d_in[40];
  const float* dl_b = (const float*)d_in[41];

  float* wsf = (float*)d_ws;
  size_t off = 0;
  auto carve = [&](size_t n) -> float* {
    float* p = wsf + off;
    off += (n + 63) & ~(size_t)63;
    return p;
  };
  const size_t SLOT = 10240000;  // 16*20000*32 floats
  float* s0 = carve(SLOT);
  float* s1 = carve(SLOT);
  float* s2 = carve(SLOT);
  float* s3 = carve(SLOT);
  float* sxl = carve(960000);
  int* deg_all = (int*)carve(26642 + 46563);
  int* deg_src_all = deg_all;
  int* deg_tgt_all = deg_all + 26642;
  int* rowptr_all = (int*)carve(46568);
  int* cursor_all = (int*)carve(46563);
  int* csrc_all = (int*)carve(159852);
  float* csw_all = carve(159852);
  float* eps = carve(1024);
  float* hcat = carve(1056);
  // monomial combo weights: enc0..enc3, dec0..dec3
  static const int CM[8] = {96, 1024, 2048, 4096, 4096, 4096, 2048, 1024};
  float* comb[8];
  for (int l = 0; l < 8; l++) comb[l] = carve((size_t)6 * CM[l]);

  static const int ROFF[5] = {0, 20001, 25002, 26253, 26567};
  static const int EOFF[5] = {0, 120000, 150000, 157500, 159378};
  auto RP = [&](int l) { return rowptr_all + ROFF[l]; };
  auto CS = [&](int l) { return csrc_all + EOFF[l]; };
  auto CW = [&](int l) { return csw_all + EOFF[l]; };

  // ---- setup: 5 launches ----
  k_zero_i<<<grid1(26642 + 46563), WG, 0, stream>>>(deg_all, 26642 + 46563);
  k_hist_all<<<grid1(159852), WG, 0, stream>>>(ep, deg_src_all, deg_tgt_all);
  k_scan_all<<<5, WG, 0, stream>>>(deg_tgt_all, rowptr_all, cursor_all);
  k_fill_all<<<625 + 4 + 3750, WG, 0, stream>>>(ep, deg_src_all, cursor_all, csrc_all,
                                                csw_all, eps, x, sxl);
  {
    WComb wc;
    for (int l = 0; l < 4; l++) { wc.w[l] = enc_w[l]; wc.c[l] = comb[l]; }
    for (int l = 0; l < 4; l++) { wc.w[4 + l] = dec_w[l]; wc.c[4 + l] = comb[4 + l]; }
    k_combine<<<grid1(18528), WG, 0, stream>>>(wc);
  }

  float* mu_out = (float*)d_out + 960000;
  float* lv_out = (float*)d_out + 961024;

  // ---- encoder (ds+relu fused into gemm via row indirection) ----
  run_cheb<3, 32>(sxl, s1, s2, s3, comb[0], enc_b[0], 20000, 5000, ds_idx[0], 0,
                  RP(0), CS(0), CW(0), stream);
  run_cheb<32, 32>(s1, s0, s2, s3, comb[1], enc_b[1], 5000, 1250, ds_idx[1], 0,
                   RP(1), CS(1), CW(1), stream);
  run_cheb<32, 64>(s0, s1, s2, s3, comb[2], enc_b[2], 1250, 313, ds_idx[2], 0,
                   RP(2), CS(2), CW(2), stream);
  run_cheb<64, 64>(s1, s0, s2, s3, comb[3], enc_b[3], 313, 79, ds_idx[3], 0,
                   RP(3), CS(3), CW(3), stream);

  // ---- latent ----
  k_latent<<<1024, 64, 0, stream>>>(s0, mu_w, mu_b, lv_w, lv_b, eps, label, mu_out, lv_out, hcat);
  k_declin<<<grid1(NB * 5056), WG, 0, stream>>>(hcat, dl_w, dl_b, s0);

  // ---- decoder ----
  k_us<64><<<grid1((long)313 * NB * 64), WG, 0, stream>>>(s0, s1, us_idx[3], us_w[3], 313);
  run_cheb<64, 64>(s1, s0, s2, s3, comb[4], dec_b[0], 313, 313, nullptr, 0,
                   RP(3), CS(3), CW(3), stream);
  k_us<64><<<grid1((long)1250 * NB * 64), WG, 0, stream>>>(s0, s1, us_idx[2], us_w[2], 1250);
  run_cheb<64, 64>(s1, s0, s2, s3, comb[5], dec_b[1], 1250, 1250, nullptr, 0,
                   RP(2), CS(2), CW(2), stream);
  k_us<64><<<grid1((long)5000 * NB * 64), WG, 0, stream>>>(s0, s1, us_idx[1], us_w[1], 5000);
  run_cheb<64, 32>(s1, s0, s2, s3, comb[6], dec_b[2], 5000, 5000, nullptr, 0,
                   RP(1), CS(1), CW(1), stream);
  k_us<32><<<grid1((long)20000 * NB * 32), WG, 0, stream>>>(s0, s1, us_idx[0], us_w[0], 20000);

  // ---- decoder level 0 (manual): pass2 fused with relu + level-4 shortcut ----
  {
    const int N = 20000;
    int rows = NB * N;  // 320000, multiple of 128
    dim3 gP((unsigned)((N + 3) / 4));
    dim3 gG((unsigned)(rows / 128));
    k_propw<32><<<gP, WG, 0, stream>>>(s1, s2, RP(0), CS(0), CW(0), N);  // Y1
    k_propw<32><<<gP, WG, 0, stream>>>(s2, s3, RP(0), CS(0), CW(0), N);  // Y2
    Ptr3 p1{{s1, s2, s3}};
    k_gemm3<32, 32><<<gG, WG, 0, stream>>>(p1, comb[7], dec_b[3], s0, rows, nullptr, 0, 0);
    k_propw<32><<<gP, WG, 0, stream>>>(s3, s1, RP(0), CS(0), CW(0), N);  // Y3
    k_propw<32><<<gP, WG, 0, stream>>>(s1, s2, RP(0), CS(0), CW(0), N);  // Y4
    k_propw<32><<<gP, WG, 0, stream>>>(s2, s3, RP(0), CS(0), CW(0), N);  // Y5
    Ptr3 p2{{s1, s2, s3}};
    k_gemm3_final<<<gG, WG, 0, stream>>>(p2, comb[7] + 3 * 32 * 32, dec_w[4], s0,
                                         (float*)d_out, rows);
  }

  // ---- exact 79-node fixup ----
  k_final_fix<<<16, 256, 0, stream>>>(s0, dec_w[4], RP(4), CS(4), CW(4), (float*)d_out);
}

// Round 13
// 1149.127 us; speedup vs baseline: 1.3975x; 1.0439x over previous
//
#include <hip/hip_runtime.h>
#include <cstdint>
#include <cstddef>

#define WG 256
#define NB 16  // batch

// Layout "L": arr[(n*16 + b)*F + f]  — node-major, batch, feature.
// Monomial basis: out = sum_j (S^j X) @ C_j (combos via k_combine).
// All fp32. Single-pass 6-term gemm used where workspace allows (bitwise
// identical to two-pass: fp32 memory round-trips are lossless).

struct IP5 { const int* e[5]; };
struct Ptr3 { const float* p[3]; };
struct Ptr6 { const float* p[6]; };
struct WComb { const float* w[8]; float* c[8]; };

static __device__ __forceinline__ void fma4(float4& a, float s, const float4& b) {
  a.x = fmaf(s, b.x, a.x); a.y = fmaf(s, b.y, a.y);
  a.z = fmaf(s, b.z, a.z); a.w = fmaf(s, b.w, a.w);
}

// ---------------- fused setup kernels ----------------

__global__ void k_zero_i(int* __restrict__ p, int n) {
  int i = blockIdx.x * WG + threadIdx.x;
  if (i < n) p[i] = 0;
}

__global__ void k_hist_all(IP5 ep, int* __restrict__ dsrc, int* __restrict__ dtgt) {
  int i = blockIdx.x * WG + threadIdx.x;
  if (i >= 159852) return;
  int l, eo, ee, no, co;
  if (i < 120000)      { l = 0; eo = 0;      ee = 120000; no = 0;     co = 0; }
  else if (i < 150000) { l = 1; eo = 120000; ee = 30000;  no = 20000; co = 20000; }
  else if (i < 157500) { l = 2; eo = 150000; ee = 7500;   no = 25000; co = 25000; }
  else if (i < 159378) { l = 3; eo = 157500; ee = 1878;   no = 26250; co = 26250; }
  else                 { l = 4; eo = 159378; ee = 474;    no = 26563; co = 26563; }
  int e = i - eo;
  const int* E = ep.e[l];
  atomicAdd(&dsrc[no + E[e]], 1);
  atomicAdd(&dtgt[co + E[ee + e]], 1);
}

__global__ void k_scan_all(const int* __restrict__ deg_all, int* __restrict__ rowptr_all,
                           int* __restrict__ cursor_all) {
  static const int Ns[5] = {20000, 5000, 1250, 313, 20000};
  static const int CO[5] = {0, 20000, 25000, 26250, 26563};
  static const int RO[5] = {0, 20001, 25002, 26253, 26567};
  __shared__ int s[WG];
  int l = blockIdx.x;
  int N = Ns[l];
  const int* deg = deg_all + CO[l];
  int* rowptr = rowptr_all + RO[l];
  int* cursor = cursor_all + CO[l];
  int t = threadIdx.x;
  int chunk = (N + WG - 1) / WG;
  int a = t * chunk;
  int b = min(N, a + chunk);
  int sum = 0;
  for (int i = a; i < b; i++) sum += deg[i];
  s[t] = sum;
  __syncthreads();
  for (int off = 1; off < WG; off <<= 1) {
    int v = (t >= off) ? s[t - off] : 0;
    __syncthreads();
    s[t] += v;
    __syncthreads();
  }
  int run = (t == 0) ? 0 : s[t - 1];
  for (int i = a; i < b; i++) {
    rowptr[i] = run;
    cursor[i] = run;
    run += deg[i];
  }
  if (t == 0) rowptr[N] = s[WG - 1];
}

// monomial-basis weight combos for all 8 cheb layers
__global__ void k_combine(WComb wc) {
  static const int M[8] = {96, 1024, 2048, 4096, 4096, 4096, 2048, 1024};
  static const int OFF[8] = {0, 96, 1120, 3168, 7264, 11360, 15456, 17504};
  int i = blockIdx.x * WG + threadIdx.x;
  if (i >= 18528) return;
  int l = 0;
  while (l < 7 && i >= OFF[l + 1]) l++;
  int e = i - OFF[l], m = M[l];
  const float* w = wc.w[l];
  float* c = wc.c[l];
  float w0 = w[e], w1 = w[m + e], w2 = w[2 * m + e];
  float w3 = w[3 * m + e], w4 = w[4 * m + e], w5 = w[5 * m + e];
  c[e]         = w0 - w2 + w4;
  c[m + e]     = w1 - 3.f * w3 + 5.f * w5;
  c[2 * m + e] = 2.f * w2 - 8.f * w4;
  c[3 * m + e] = 4.f * w3 - 20.f * w5;
  c[4 * m + e] = 8.f * w4;
  c[5 * m + e] = 16.f * w5;
}

// ---------------- threefry eps (verified vs harness JAX ref) ----------------

static __device__ __forceinline__ float erfinv_f(float x) {
  float w = -log1pf(-x * x);
  float p;
  if (w < 5.0f) {
    w -= 2.5f;
    p = 2.81022636e-08f;
    p = fmaf(p, w, 3.43273939e-07f);
    p = fmaf(p, w, -3.5233877e-06f);
    p = fmaf(p, w, -4.39150654e-06f);
    p = fmaf(p, w, 0.00021858087f);
    p = fmaf(p, w, -0.00125372503f);
    p = fmaf(p, w, -0.00417768164f);
    p = fmaf(p, w, 0.246640727f);
    p = fmaf(p, w, 1.50140941f);
  } else {
    w = sqrtf(w) - 3.0f;
    p = -0.000200214257f;
    p = fmaf(p, w, 0.000100950558f);
    p = fmaf(p, w, 0.00134934322f);
    p = fmaf(p, w, -0.00367342844f);
    p = fmaf(p, w, 0.00573950773f);
    p = fmaf(p, w, -0.0076224613f);
    p = fmaf(p, w, 0.00943887047f);
    p = fmaf(p, w, 1.00167406f);
    p = fmaf(p, w, 2.83297682f);
  }
  return p * x;
}

static __device__ __forceinline__ float bits_to_normal(unsigned b) {
  float f = __uint_as_float((b >> 9) | 0x3f800000u) - 1.0f;
  const float lo = -0.99999994f;
  float u = f * (1.0f - lo) + lo;
  u = fmaxf(u, lo);
  return 1.41421356f * erfinv_f(u);
}

static __device__ __forceinline__ float eps_val(int i) {
  unsigned x0 = 0u, x1 = (unsigned)i;
  unsigned ks[3] = {0u, 42u, 0u ^ 42u ^ 0x1BD11BDAu};
  x0 += ks[0];
  x1 += ks[1];
  const int R[2][4] = {{13, 15, 26, 6}, {17, 29, 16, 24}};
#pragma unroll
  for (int it = 0; it < 5; it++) {
#pragma unroll
    for (int j = 0; j < 4; j++) {
      x0 += x1;
      int r = R[it & 1][j];
      x1 = (x1 << r) | (x1 >> (32 - r));
      x1 ^= x0;
    }
    x0 += ks[(it + 1) % 3];
    x1 += ks[(it + 2) % 3] + (unsigned)(it + 1);
  }
  return bits_to_normal(x0 ^ x1);
}

__global__ void k_fill_all(IP5 ep, const int* __restrict__ dsrc, int* __restrict__ cursor,
                           int* __restrict__ csrc, float* __restrict__ csw,
                           float* __restrict__ eps, const float* __restrict__ x,
                           float* __restrict__ sxl) {
  int blk = blockIdx.x;
  if (blk < 625) {
    int i = blk * WG + threadIdx.x;
    if (i >= 159852) return;
    int l, eo, ee, no, co, eb;
    if (i < 120000)      { l = 0; eo = 0;      ee = 120000; no = 0;     co = 0;     eb = 0; }
    else if (i < 150000) { l = 1; eo = 120000; ee = 30000;  no = 20000; co = 20000; eb = 120000; }
    else if (i < 157500) { l = 2; eo = 150000; ee = 7500;   no = 25000; co = 25000; eb = 150000; }
    else if (i < 159378) { l = 3; eo = 157500; ee = 1878;   no = 26250; co = 26250; eb = 157500; }
    else                 { l = 4; eo = 159378; ee = 474;    no = 26563; co = 26563; eb = 159378; }
    int e = i - eo;
    const int* E = ep.e[l];
    int s = E[e], t = E[ee + e];
    float da = (float)dsrc[no + s], db = (float)dsrc[no + t];
    float wa = (da > 0.f) ? (1.0f / sqrtf(da)) : 0.f;
    float wb = (db > 0.f) ? (1.0f / sqrtf(db)) : 0.f;
    int pos = atomicAdd(&cursor[co + t], 1);
    csrc[eb + pos] = s;
    csw[eb + pos] = wa * wb;
  } else if (blk < 629) {
    int j = (blk - 625) * WG + threadIdx.x;
    if (j < 1024) eps[j] = eps_val(j);
  } else {
    int j = (blk - 629) * WG + threadIdx.x;
    if (j >= NB * 20000 * 3) return;
    int f = j % 3;
    int b = (j / 3) % NB;
    int n = j / 48;
    sxl[j] = x[((size_t)b * 20000 + n) * 3 + f];
  }
}

// ---------------- wave-per-node propagation: out = S * in ----------------

#define RFL_I(v) __builtin_amdgcn_readfirstlane(v)
#define RFL_F(v) __int_as_float(__builtin_amdgcn_readfirstlane(__float_as_int(v)))

template <int F>
__global__ __launch_bounds__(WG) void k_propw(const float* __restrict__ in,
                                              float* __restrict__ out,
                                              const int* __restrict__ rowptr,
                                              const int* __restrict__ csrc,
                                              const float* __restrict__ csw, int N) {
  constexpr int C4 = F / 16;
  int node = blockIdx.x * 4 + (threadIdx.x >> 6);
  if (node >= N) return;
  int lane = threadIdx.x & 63;
  const float4* in4 = (const float4*)in;
  float4 acc[C4];
#pragma unroll
  for (int u = 0; u < C4; u++) acc[u] = make_float4(0.f, 0.f, 0.f, 0.f);
  int beg = rowptr[node], end = rowptr[node + 1];
  int j = beg;
  for (; j + 3 < end; j += 4) {
    int s0 = RFL_I(csrc[j]);
    int s1 = RFL_I(csrc[j + 1]);
    int s2 = RFL_I(csrc[j + 2]);
    int s3 = RFL_I(csrc[j + 3]);
    float w0 = RFL_F(csw[j]);
    float w1 = RFL_F(csw[j + 1]);
    float w2 = RFL_F(csw[j + 2]);
    float w3 = RFL_F(csw[j + 3]);
    const float4* p0 = in4 + (size_t)s0 * (4 * F) + lane;
    const float4* p1 = in4 + (size_t)s1 * (4 * F) + lane;
    const float4* p2 = in4 + (size_t)s2 * (4 * F) + lane;
    const float4* p3 = in4 + (size_t)s3 * (4 * F) + lane;
    float4 v0[C4], v1[C4], v2[C4], v3[C4];
#pragma unroll
    for (int u = 0; u < C4; u++) v0[u] = p0[u * 64];
#pragma unroll
    for (int u = 0; u < C4; u++) v1[u] = p1[u * 64];
#pragma unroll
    for (int u = 0; u < C4; u++) v2[u] = p2[u * 64];
#pragma unroll
    for (int u = 0; u < C4; u++) v3[u] = p3[u * 64];
#pragma unroll
    for (int u = 0; u < C4; u++) {
      fma4(acc[u], w0, v0[u]);
      fma4(acc[u], w1, v1[u]);
      fma4(acc[u], w2, v2[u]);
      fma4(acc[u], w3, v3[u]);
    }
  }
  for (; j < end; j++) {
    int s0 = RFL_I(csrc[j]);
    float w0 = RFL_F(csw[j]);
    const float4* p0 = in4 + (size_t)s0 * (4 * F) + lane;
#pragma unroll
    for (int u = 0; u < C4; u++) {
      float4 v0 = p0[u * 64];
      fma4(acc[u], w0, v0);
    }
  }
  float4* o4 = (float4*)out + (size_t)node * (4 * F) + lane;
#pragma unroll
  for (int u = 0; u < C4; u++) o4[u * 64] = acc[u];
}

// F=3 variant
__global__ __launch_bounds__(WG) void k_propw3(const float* __restrict__ in,
                                               float* __restrict__ out,
                                               const int* __restrict__ rowptr,
                                               const int* __restrict__ csrc,
                                               const float* __restrict__ csw, int N) {
  int node = blockIdx.x * 4 + (threadIdx.x >> 6);
  if (node >= N) return;
  int lane = threadIdx.x & 63;
  if (lane >= 48) return;
  float acc = 0.f;
  int beg = rowptr[node], end = rowptr[node + 1];
  for (int j = beg; j < end; j++) {
    int s = RFL_I(csrc[j]);
    float w = RFL_F(csw[j]);
    acc = fmaf(w, in[(size_t)s * 48 + lane], acc);
  }
  out[(size_t)node * 48 + lane] = acc;
}

// ---------------- fused 3-term GEMM, 4 rows x 4 cols per thread ----------------

template <int F, int G>
__global__ __launch_bounds__(WG) void k_gemm3(Ptr3 txs, const float* __restrict__ W,
                                              const float* __restrict__ bias,
                                              float* __restrict__ out, int rows,
                                              const int* __restrict__ idx,
                                              int accum, int relu) {
  constexpr int CG = G / 4;
  constexpr int RT = WG / CG;
  constexpr int RPB = RT * 4;
  __shared__ float sW[3 * F * G];
  for (int i = threadIdx.x; i < 3 * F * G; i += WG) sW[i] = W[i];
  __syncthreads();
  int cg = threadIdx.x % CG;
  int rt = threadIdx.x / CG;
  int row0 = blockIdx.x * RPB + rt * 4;
  if (row0 >= rows) return;
  size_t src0 = row0;
  if (idx) {
    int node = row0 >> 4, b = row0 & 15;
    src0 = (size_t)idx[node] * 16 + b;
  }
  float* o = out + (size_t)row0 * G + cg * 4;
  float4 acc[4];
  if (accum) {
#pragma unroll
    for (int r = 0; r < 4; r++) acc[r] = *(const float4*)(o + (size_t)r * G);
  } else if (bias) {
    float4 bv = *(const float4*)(bias + cg * 4);
#pragma unroll
    for (int r = 0; r < 4; r++) acc[r] = bv;
  } else {
#pragma unroll
    for (int r = 0; r < 4; r++) acc[r] = make_float4(0.f, 0.f, 0.f, 0.f);
  }
#pragma unroll
  for (int kk = 0; kk < 3; kk++) {
    const float* tb = txs.p[kk] + src0 * F;
    const float* w = sW + kk * F * G + cg * 4;
    if constexpr (F == 3) {
      float4 w0 = *(const float4*)(w + 0 * G);
      float4 w1 = *(const float4*)(w + 1 * G);
      float4 w2 = *(const float4*)(w + 2 * G);
#pragma unroll
      for (int r = 0; r < 4; r++) {
        float x0 = tb[r * 3 + 0], x1 = tb[r * 3 + 1], x2 = tb[r * 3 + 2];
        fma4(acc[r], x0, w0);
        fma4(acc[r], x1, w1);
        fma4(acc[r], x2, w2);
      }
    } else {
#pragma unroll
      for (int fg = 0; fg < F / 4; fg++) {
        float4 xv[4];
#pragma unroll
        for (int r = 0; r < 4; r++) xv[r] = *(const float4*)(tb + (size_t)r * F + 4 * fg);
        float4 w0 = *(const float4*)(w + (4 * fg + 0) * G);
        float4 w1 = *(const float4*)(w + (4 * fg + 1) * G);
        float4 w2 = *(const float4*)(w + (4 * fg + 2) * G);
        float4 w3 = *(const float4*)(w + (4 * fg + 3) * G);
#pragma unroll
        for (int r = 0; r < 4; r++) {
          fma4(acc[r], xv[r].x, w0);
          fma4(acc[r], xv[r].y, w1);
          fma4(acc[r], xv[r].z, w2);
          fma4(acc[r], xv[r].w, w3);
        }
      }
    }
  }
  if (relu) {
#pragma unroll
    for (int r = 0; r < 4; r++) {
      acc[r].x = fmaxf(acc[r].x, 0.f); acc[r].y = fmaxf(acc[r].y, 0.f);
      acc[r].z = fmaxf(acc[r].z, 0.f); acc[r].w = fmaxf(acc[r].w, 0.f);
    }
  }
#pragma unroll
  for (int r = 0; r < 4; r++) *(float4*)(o + (size_t)r * G) = acc[r];
}

// ---------------- single-pass 6-term GEMM, G=32 (F=3 or F=32) ----------------

template <int F>
__global__ __launch_bounds__(WG) void k_gemm6(Ptr6 txs, const float* __restrict__ W,
                                              const float* __restrict__ bias,
                                              float* __restrict__ out, int rows,
                                              const int* __restrict__ idx, int relu) {
  constexpr int G = 32;
  __shared__ float sW[6 * F * G];
  for (int i = threadIdx.x; i < 6 * F * G; i += WG) sW[i] = W[i];
  __syncthreads();
  int cg = threadIdx.x & 7;
  int rt = threadIdx.x >> 3;
  int row0 = blockIdx.x * 128 + rt * 4;
  if (row0 >= rows) return;
  size_t src0 = row0;
  if (idx) {
    int node = row0 >> 4, b = row0 & 15;
    src0 = (size_t)idx[node] * 16 + b;
  }
  float* o = out + (size_t)row0 * G + cg * 4;
  float4 acc[4];
  float4 bv = *(const float4*)(bias + cg * 4);
#pragma unroll
  for (int r = 0; r < 4; r++) acc[r] = bv;
#pragma unroll
  for (int kk = 0; kk < 6; kk++) {
    const float* tb = txs.p[kk] + src0 * F;
    const float* w = sW + kk * F * G + cg * 4;
    if constexpr (F == 3) {
      float4 w0 = *(const float4*)(w + 0 * G);
      float4 w1 = *(const float4*)(w + 1 * G);
      float4 w2 = *(const float4*)(w + 2 * G);
#pragma unroll
      for (int r = 0; r < 4; r++) {
        float x0 = tb[r * 3 + 0], x1 = tb[r * 3 + 1], x2 = tb[r * 3 + 2];
        fma4(acc[r], x0, w0);
        fma4(acc[r], x1, w1);
        fma4(acc[r], x2, w2);
      }
    } else {
#pragma unroll
      for (int fg = 0; fg < F / 4; fg++) {
        float4 xv[4];
#pragma unroll
        for (int r = 0; r < 4; r++) xv[r] = *(const float4*)(tb + (size_t)r * F + 4 * fg);
        float4 w0 = *(const float4*)(w + (4 * fg + 0) * G);
        float4 w1 = *(const float4*)(w + (4 * fg + 1) * G);
        float4 w2 = *(const float4*)(w + (4 * fg + 2) * G);
        float4 w3 = *(const float4*)(w + (4 * fg + 3) * G);
#pragma unroll
        for (int r = 0; r < 4; r++) {
          fma4(acc[r], xv[r].x, w0);
          fma4(acc[r], xv[r].y, w1);
          fma4(acc[r], xv[r].z, w2);
          fma4(acc[r], xv[r].w, w3);
        }
      }
    }
  }
  if (relu) {
#pragma unroll
    for (int r = 0; r < 4; r++) {
      acc[r].x = fmaxf(acc[r].x, 0.f); acc[r].y = fmaxf(acc[r].y, 0.f);
      acc[r].z = fmaxf(acc[r].z, 0.f); acc[r].w = fmaxf(acc[r].w, 0.f);
    }
  }
#pragma unroll
  for (int r = 0; r < 4; r++) *(float4*)(o + (size_t)r * G) = acc[r];
}

// ---- decoder L0 single-pass: 6 terms + bias + relu + level-4 shortcut ----
// writes fp32 fixbuf rows for nodes<79 and fp32 dout. rows % 128 == 0.
__global__ __launch_bounds__(WG) void k_gemm6f(Ptr6 txs, const float* __restrict__ W,
                                               const float* __restrict__ bias,
                                               const float* __restrict__ W4,
                                               float* __restrict__ fixbuf,
                                               float* __restrict__ dout, int rows) {
  constexpr int F = 32, G = 32;
  __shared__ float sW[6 * F * G];
  __shared__ float sWc[96];
  for (int i = threadIdx.x; i < 6 * F * G; i += WG) sW[i] = W[i];
  if (threadIdx.x < 96)
    sWc[threadIdx.x] = W4[threadIdx.x] - W4[192 + threadIdx.x] + W4[384 + threadIdx.x];
  __syncthreads();
  int cg = threadIdx.x & 7;
  int rt = threadIdx.x >> 3;
  int row0 = blockIdx.x * 128 + rt * 4;
  float4 acc[4];
  float4 bv = *(const float4*)(bias + cg * 4);
#pragma unroll
  for (int r = 0; r < 4; r++) acc[r] = bv;
#pragma unroll
  for (int kk = 0; kk < 6; kk++) {
    const float* tb = txs.p[kk] + (size_t)row0 * F;
    const float* w = sW + kk * F * G + cg * 4;
#pragma unroll
    for (int fg = 0; fg < F / 4; fg++) {
      float4 xv[4];
#pragma unroll
      for (int r = 0; r < 4; r++) xv[r] = *(const float4*)(tb + (size_t)r * F + 4 * fg);
      float4 w0 = *(const float4*)(w + (4 * fg + 0) * G);
      float4 w1 = *(const float4*)(w + (4 * fg + 1) * G);
      float4 w2 = *(const float4*)(w + (4 * fg + 2) * G);
      float4 w3 = *(const float4*)(w + (4 * fg + 3) * G);
#pragma unroll
      for (int r = 0; r < 4; r++) {
        fma4(acc[r], xv[r].x, w0);
        fma4(acc[r], xv[r].y, w1);
        fma4(acc[r], xv[r].z, w2);
        fma4(acc[r], xv[r].w, w3);
      }
    }
  }
#pragma unroll
  for (int r = 0; r < 4; r++) {
    acc[r].x = fmaxf(acc[r].x, 0.f); acc[r].y = fmaxf(acc[r].y, 0.f);
    acc[r].z = fmaxf(acc[r].z, 0.f); acc[r].w = fmaxf(acc[r].w, 0.f);
  }
  // fp32 slice for final_fix (nodes < 79); 4-row group never crosses a node
  if ((row0 >> 4) < 79) {
#pragma unroll
    for (int r = 0; r < 4; r++)
      *(float4*)(fixbuf + (size_t)(row0 + r) * 32 + cg * 4) = acc[r];
  }
  // level-4 shortcut: per-row 3-wide output, reduced across the 8 cg lanes
#pragma unroll
  for (int r = 0; r < 4; r++) {
    float av[4] = {acc[r].x, acc[r].y, acc[r].z, acc[r].w};
    float p0 = 0.f, p1 = 0.f, p2 = 0.f;
#pragma unroll
    for (int j = 0; j < 4; j++) {
      int f = cg * 4 + j;
      p0 = fmaf(av[j], sWc[f * 3 + 0], p0);
      p1 = fmaf(av[j], sWc[f * 3 + 1], p1);
      p2 = fmaf(av[j], sWc[f * 3 + 2], p2);
    }
#pragma unroll
    for (int m = 4; m >= 1; m >>= 1) {
      p0 += __shfl_xor(p0, m, 64);
      p1 += __shfl_xor(p1, m, 64);
      p2 += __shfl_xor(p2, m, 64);
    }
    if (cg == 0) {
      int row = row0 + r;
      int n = row >> 4, b = row & 15;
      float* od = dout + ((size_t)b * 20000 + n) * 3;
      od[0] = p0; od[1] = p1; od[2] = p2;
    }
  }
}

// two-pass L0 pass2 (fallback path)
__global__ __launch_bounds__(WG) void k_gemm3_final(Ptr3 txs, const float* __restrict__ W,
                                                    const float* __restrict__ W4,
                                                    float* __restrict__ out,
                                                    float* __restrict__ dout, int rows) {
  constexpr int F = 32, G = 32;
  __shared__ float sW[3 * F * G];
  __shared__ float sWc[96];
  for (int i = threadIdx.x; i < 3 * F * G; i += WG) sW[i] = W[i];
  if (threadIdx.x < 96)
    sWc[threadIdx.x] = W4[threadIdx.x] - W4[192 + threadIdx.x] + W4[384 + threadIdx.x];
  __syncthreads();
  int cg = threadIdx.x & 7;
  int rt = threadIdx.x >> 3;
  int row0 = blockIdx.x * 128 + rt * 4;
  float* o = out + (size_t)row0 * G + cg * 4;
  float4 acc[4];
#pragma unroll
  for (int r = 0; r < 4; r++) acc[r] = *(const float4*)(o + (size_t)r * G);
#pragma unroll
  for (int kk = 0; kk < 3; kk++) {
    const float* tb = txs.p[kk] + (size_t)row0 * F;
    const float* w = sW + kk * F * G + cg * 4;
#pragma unroll
    for (int fg = 0; fg < F / 4; fg++) {
      float4 xv[4];
#pragma unroll
      for (int r = 0; r < 4; r++) xv[r] = *(const float4*)(tb + (size_t)r * F + 4 * fg);
      float4 w0 = *(const float4*)(w + (4 * fg + 0) * G);
      float4 w1 = *(const float4*)(w + (4 * fg + 1) * G);
      float4 w2 = *(const float4*)(w + (4 * fg + 2) * G);
      float4 w3 = *(const float4*)(w + (4 * fg + 3) * G);
#pragma unroll
      for (int r = 0; r < 4; r++) {
        fma4(acc[r], xv[r].x, w0);
        fma4(acc[r], xv[r].y, w1);
        fma4(acc[r], xv[r].z, w2);
        fma4(acc[r], xv[r].w, w3);
      }
    }
  }
#pragma unroll
  for (int r = 0; r < 4; r++) {
    acc[r].x = fmaxf(acc[r].x, 0.f); acc[r].y = fmaxf(acc[r].y, 0.f);
    acc[r].z = fmaxf(acc[r].z, 0.f); acc[r].w = fmaxf(acc[r].w, 0.f);
  }
  if ((row0 >> 4) < 79) {
#pragma unroll
    for (int r = 0; r < 4; r++) *(float4*)(o + (size_t)r * G) = acc[r];
  }
#pragma unroll
  for (int r = 0; r < 4; r++) {
    float av[4] = {acc[r].x, acc[r].y, acc[r].z, acc[r].w};
    float p0 = 0.f, p1 = 0.f, p2 = 0.f;
#pragma unroll
    for (int j = 0; j < 4; j++) {
      int f = cg * 4 + j;
      p0 = fmaf(av[j], sWc[f * 3 + 0], p0);
      p1 = fmaf(av[j], sWc[f * 3 + 1], p1);
      p2 = fmaf(av[j], sWc[f * 3 + 2], p2);
    }
#pragma unroll
    for (int m = 4; m >= 1; m >>= 1) {
      p0 += __shfl_xor(p0, m, 64);
      p1 += __shfl_xor(p1, m, 64);
      p2 += __shfl_xor(p2, m, 64);
    }
    if (cg == 0) {
      int row = row0 + r;
      int n = row >> 4, b = row & 15;
      float* od = dout + ((size_t)b * 20000 + n) * 3;
      od[0] = p0; od[1] = p1; od[2] = p2;
    }
  }
}

// exact K=6 Chebyshev fixup for the 79 real nodes (fp32 in, T-basis).
__global__ __launch_bounds__(256) void k_final_fix(const float* __restrict__ in,
                                                   const float* __restrict__ W,  // 6x32x3
                                                   const int* __restrict__ rowptr,
                                                   const int* __restrict__ csrc,
                                                   const float* __restrict__ csw,
                                                   float* __restrict__ out) {
  __shared__ float B0[79 * 32], B1[79 * 32], B2[79 * 32];
  __shared__ float sacc[79 * 3];
  __shared__ float sW[576];
  int b = blockIdx.x, t = threadIdx.x;
  for (int i = t; i < 576; i += 256) sW[i] = W[i];
  for (int i = t; i < 2528; i += 256) {
    int r = i >> 5, f = i & 31;
    B0[i] = in[((size_t)r * 16 + b) * 32 + f];
  }
  __syncthreads();
  for (int i = t; i < 237; i += 256) {
    int r = i / 3, g = i % 3;
    float a = 0.f;
    for (int f = 0; f < 32; f++) a = fmaf(B0[r * 32 + f], sW[f * 3 + g], a);
    sacc[i] = a;
  }
  for (int i = t; i < 2528; i += 256) {
    int r = i >> 5, f = i & 31;
    float a = 0.f;
    for (int j = rowptr[r]; j < rowptr[r + 1]; j++) a = fmaf(csw[j], B0[csrc[j] * 32 + f], a);
    B1[i] = a;
  }
  __syncthreads();
  for (int i = t; i < 237; i += 256) {
    int r = i / 3, g = i % 3;
    float a = sacc[i];
    for (int f = 0; f < 32; f++) a = fmaf(B1[r * 32 + f], sW[96 + f * 3 + g], a);
    sacc[i] = a;
  }
  for (int i = t; i < 2528; i += 256) {
    int r = i >> 5, f = i & 31;
    float a = 0.f;
    for (int j = rowptr[r]; j < rowptr[r + 1]; j++) a = fmaf(csw[j], B1[csrc[j] * 32 + f], a);
    B2[i] = 2.f * a - B0[i];
  }
  __syncthreads();
  for (int i = t; i < 237; i += 256) {
    int r = i / 3, g = i % 3;
    float a = sacc[i];
    for (int f = 0; f < 32; f++) a = fmaf(B2[r * 32 + f], sW[192 + f * 3 + g], a);
    sacc[i] = a;
  }
  __syncthreads();
  for (int i = t; i < 2528; i += 256) {
    int r = i >> 5, f = i & 31;
    float a = 0.f;
    for (int j = rowptr[r]; j < rowptr[r + 1]; j++) a = fmaf(csw[j], B2[csrc[j] * 32 + f], a);
    B0[i] = 2.f * a - B1[i];
  }
  __syncthreads();
  for (int i = t; i < 237; i += 256) {
    int r = i / 3, g = i % 3;
    float a = sacc[i];
    for (int f = 0; f < 32; f++) a = fmaf(B0[r * 32 + f], sW[288 + f * 3 + g], a);
    sacc[i] = a;
  }
  __syncthreads();
  for (int i = t; i < 2528; i += 256) {
    int r = i >> 5, f = i & 31;
    float a = 0.f;
    for (int j = rowptr[r]; j < rowptr[r + 1]; j++) a = fmaf(csw[j], B0[csrc[j] * 32 + f], a);
    B1[i] = 2.f * a - B2[i];
  }
  __syncthreads();
  for (int i = t; i < 237; i += 256) {
    int r = i / 3, g = i % 3;
    float a = sacc[i];
    for (int f = 0; f < 32; f++) a = fmaf(B1[r * 32 + f], sW[384 + f * 3 + g], a);
    sacc[i] = a;
  }
  __syncthreads();
  for (int i = t; i < 2528; i += 256) {
    int r = i >> 5, f = i & 31;
    float a = 0.f;
    for (int j = rowptr[r]; j < rowptr[r + 1]; j++) a = fmaf(csw[j], B1[csrc[j] * 32 + f], a);
    B2[i] = 2.f * a - B0[i];
  }
  __syncthreads();
  for (int i = t; i < 237; i += 256) {
    int r = i / 3, g = i % 3;
    float a = sacc[i];
    for (int f = 0; f < 32; f++) a = fmaf(B2[r * 32 + f], sW[480 + f * 3 + g], a);
    out[((size_t)b * 20000 + r) * 3 + g] = a;
  }
}

// upsample (relu fused on input)
template <int F>
__global__ __launch_bounds__(WG) void k_us(const float* __restrict__ in,
                                           float* __restrict__ out,
                                           const int* __restrict__ uidx,
                                           const float* __restrict__ uw, int Nf) {
  int i = blockIdx.x * WG + threadIdx.x;
  int total = Nf * NB * F;
  if (i >= total) return;
  int pos = i % (NB * F);
  int r = i / (NB * F);
  float acc = 0.f;
#pragma unroll
  for (int k = 0; k < 3; k++) {
    float v = in[(size_t)uidx[r * 3 + k] * NB * F + pos];
    acc = fmaf(uw[r * 3 + k], fmaxf(v, 0.f), acc);
  }
  out[i] = acc;
}

// ---------------- latent kernels (L layout h: (79,16,64)) ----------------

__global__ __launch_bounds__(64) void k_latent(const float* __restrict__ h,
                                               const float* __restrict__ muW,
                                               const float* __restrict__ muB,
                                               const float* __restrict__ lvW,
                                               const float* __restrict__ lvB,
                                               const float* __restrict__ eps,
                                               const float* __restrict__ label,
                                               float* __restrict__ mu_out,
                                               float* __restrict__ lv_out,
                                               float* __restrict__ hcat) {
  int b = blockIdx.x / 64;
  int g = blockIdx.x % 64;
  int l = threadIdx.x;
  float am = 0.f, al = 0.f;
  for (int i = l; i < 5056; i += 64) {
    int n = i >> 6, f = i & 63;
    float hv = h[(size_t)(n * 16 + b) * 64 + f];
    am = fmaf(hv, muW[(size_t)i * 64 + g], am);
    al = fmaf(hv, lvW[(size_t)i * 64 + g], al);
  }
  for (int off = 32; off > 0; off >>= 1) {
    am += __shfl_down(am, off, 64);
    al += __shfl_down(al, off, 64);
  }
  if (l == 0) {
    am += muB[g];
    al += lvB[g];
    mu_out[b * 64 + g] = am;
    lv_out[b * 64 + g] = al;
    hcat[b * 66 + g] = fmaf(eps[b * 64 + g], expf(0.5f * al), am);
    if (g < 2) hcat[b * 66 + 64 + g] = label[b * 2 + g];
  }
}

__global__ __launch_bounds__(WG) void k_declin(const float* __restrict__ hcat,
                                               const float* __restrict__ W,
                                               const float* __restrict__ bias,
                                               float* __restrict__ out) {
  int idx = blockIdx.x * WG + threadIdx.x;
  if (idx >= NB * 5056) return;
  int b = idx / 5056, j = idx % 5056;
  int n = j >> 6, f = j & 63;
  float acc = bias[j];
  const float* hc = hcat + b * 66;
#pragma unroll
  for (int i = 0; i < 66; i++) acc = fmaf(hc[i], W[(size_t)i * 5056 + j], acc);
  out[(size_t)(n * 16 + b) * 64 + f] = fmaxf(acc, 0.f);
}

// ---------------- host orchestration ----------------

static inline dim3 grid1(long n) { return dim3((unsigned)((n + WG - 1) / WG)); }

// two-pass monomial cheb layer
template <int F, int G>
static void run_cheb(float* in, float* out, float* A, float* B,
                     const float* C, const float* bias, int N, int Nout,
                     const int* ds_idx, int relu_last,
                     const int* rowptr, const int* csrc, const float* csw,
                     hipStream_t st) {
  int orows = NB * Nout;
  dim3 gP((unsigned)((N + 3) / 4));
  constexpr int RPB = (WG / (G / 4)) * 4;
  dim3 gG((unsigned)((orows + RPB - 1) / RPB));
  int relu2 = ds_idx ? 1 : relu_last;
  if constexpr (F == 3) {
    k_propw3<<<gP, WG, 0, st>>>(in, A, rowptr, csrc, csw, N);
    k_propw3<<<gP, WG, 0, st>>>(A, B, rowptr, csrc, csw, N);
    Ptr3 p1{{in, A, B}};
    k_gemm3<F, G><<<gG, WG, 0, st>>>(p1, C, bias, out, orows, ds_idx, 0, 0);
    k_propw3<<<gP, WG, 0, st>>>(B, in, rowptr, csrc, csw, N);
    k_propw3<<<gP, WG, 0, st>>>(in, A, rowptr, csrc, csw, N);
    k_propw3<<<gP, WG, 0, st>>>(A, B, rowptr, csrc, csw, N);
    Ptr3 p2{{in, A, B}};
    k_gemm3<F, G><<<gG, WG, 0, st>>>(p2, C + 3 * F * G, nullptr, out, orows, ds_idx, 1, relu2);
  } else {
    k_propw<F><<<gP, WG, 0, st>>>(in, A, rowptr, csrc, csw, N);
    k_propw<F><<<gP, WG, 0, st>>>(A, B, rowptr, csrc, csw, N);
    Ptr3 p1{{in, A, B}};
    k_gemm3<F, G><<<gG, WG, 0, st>>>(p1, C, bias, out, orows, ds_idx, 0, 0);
    k_propw<F><<<gP, WG, 0, st>>>(B, in, rowptr, csrc, csw, N);
    k_propw<F><<<gP, WG, 0, st>>>(in, A, rowptr, csrc, csw, N);
    k_propw<F><<<gP, WG, 0, st>>>(A, B, rowptr, csrc, csw, N);
    Ptr3 p2{{in, A, B}};
    k_gemm3<F, G><<<gG, WG, 0, st>>>(p2, C + 3 * F * G, nullptr, out, orows, ds_idx, 1, relu2);
  }
}

// single-pass cheb layer (G=32): 5 props into Y[0..4]=Y1..Y5, one gemm6
template <int F>
static void run_cheb6(float* in, float* out, float* const* Y,
                      const float* C, const float* bias, int N, int Nout,
                      const int* ds_idx, int relu,
                      const int* rowptr, const int* csrc, const float* csw,
                      hipStream_t st) {
  int orows = NB * Nout;
  dim3 gP((unsigned)((N + 3) / 4));
  dim3 gG((unsigned)((orows + 127) / 128));
  if constexpr (F == 3) {
    k_propw3<<<gP, WG, 0, st>>>(in, Y[0], rowptr, csrc, csw, N);
    k_propw3<<<gP, WG, 0, st>>>(Y[0], Y[1], rowptr, csrc, csw, N);
    k_propw3<<<gP, WG, 0, st>>>(Y[1], Y[2], rowptr, csrc, csw, N);
    k_propw3<<<gP, WG, 0, st>>>(Y[2], Y[3], rowptr, csrc, csw, N);
    k_propw3<<<gP, WG, 0, st>>>(Y[3], Y[4], rowptr, csrc, csw, N);
  } else {
    k_propw<F><<<gP, WG, 0, st>>>(in, Y[0], rowptr, csrc, csw, N);
    k_propw<F><<<gP, WG, 0, st>>>(Y[0], Y[1], rowptr, csrc, csw, N);
    k_propw<F><<<gP, WG, 0, st>>>(Y[1], Y[2], rowptr, csrc, csw, N);
    k_propw<F><<<gP, WG, 0, st>>>(Y[2], Y[3], rowptr, csrc, csw, N);
    k_propw<F><<<gP, WG, 0, st>>>(Y[3], Y[4], rowptr, csrc, csw, N);
  }
  Ptr6 p{{in, Y[0], Y[1], Y[2], Y[3], Y[4]}};
  k_gemm6<F><<<gG, WG, 0, st>>>(p, C, bias, out, orows, ds_idx, relu);
}

extern "C" void kernel_launch(void* const* d_in, const int* in_sizes, int n_in,
                              void* d_out, int out_size, void* d_ws, size_t ws_size,
                              hipStream_t stream) {
  const float* x = (const float*)d_in[0];
  const float* label = (const float*)d_in[1];
  IP5 ep;
  for (int l = 0; l < 5; l++) ep.e[l] = (const int*)d_in[2 + l];
  const int* ds_idx[4];
  const int* us_idx[4];
  const float* us_w[4];
  for (int i = 0; i < 4; i++) {
    ds_idx[i] = (const int*)d_in[7 + 3 * i];
    us_idx[i] = (const int*)d_in[8 + 3 * i];
    us_w[i] = (const float*)d_in[9 + 3 * i];
  }
  const float* enc_w[4];
  const float* enc_b[4];
  for (int i = 0; i < 4; i++) {
    enc_w[i] = (const float*)d_in[19 + 2 * i];
    enc_b[i] = (const float*)d_in[20 + 2 * i];
  }
  const float* dec_w[5];
  for (int i = 0; i < 5; i++) dec_w[i] = (const float*)d_in[27 + i];
  const float* dec_b[4];
  for (int i = 0; i < 4; i++) dec_b[i] = (const float*)d_in[32 + i];
  const float* mu_w = (const float*)d_in[36];
  const float* mu_b = (const float*)d_in[37];
  const float* lv_w = (const float*)d_in[38];
  const float* lv_b = (const float*)d_in[39];
  const float* dl_w = (const float*)d_in[40];
  const float* dl_b = (const float*)d_in[41];

  float* wsf = (float*)d_ws;
  size_t off = 0;
  auto carve = [&](size_t n) -> float* {
    float* p = wsf + off;
    off += (n + 63) & ~(size_t)63;
    return p;
  };
  const size_t SLOT = 10240000;  // 16*20000*32 floats
  float* s0 = carve(SLOT);
  float* s1 = carve(SLOT);
  float* s2 = carve(SLOT);
  float* s3 = carve(SLOT);
  float* sxl = carve(960000);
  int* deg_all = (int*)carve(26642 + 46563);
  int* deg_src_all = deg_all;
  int* deg_tgt_all = deg_all + 26642;
  int* rowptr_all = (int*)carve(46568);
  int* cursor_all = (int*)carve(46563);
  int* csrc_all = (int*)carve(159852);
  float* csw_all = carve(159852);
  float* eps = carve(1024);
  float* hcat = carve(1056);
  float* fixbuf = carve(79 * 16 * 32);
  static const int CM[8] = {96, 1024, 2048, 4096, 4096, 4096, 2048, 1024};
  float* comb[8];
  for (int l = 0; l < 8; l++) comb[l] = carve((size_t)6 * CM[l]);
  // extra big slots for the single-pass (6-buffer) path
  float* s4 = carve(SLOT);
  float* s5 = carve(SLOT);
  bool fused = (off * sizeof(float)) <= ws_size;

  static const int ROFF[5] = {0, 20001, 25002, 26253, 26567};
  static const int EOFF[5] = {0, 120000, 150000, 157500, 159378};
  auto RP = [&](int l) { return rowptr_all + ROFF[l]; };
  auto CS = [&](int l) { return csrc_all + EOFF[l]; };
  auto CW = [&](int l) { return csw_all + EOFF[l]; };

  // ---- setup: 5 launches ----
  k_zero_i<<<grid1(26642 + 46563), WG, 0, stream>>>(deg_all, 26642 + 46563);
  k_hist_all<<<grid1(159852), WG, 0, stream>>>(ep, deg_src_all, deg_tgt_all);
  k_scan_all<<<5, WG, 0, stream>>>(deg_tgt_all, rowptr_all, cursor_all);
  k_fill_all<<<625 + 4 + 3750, WG, 0, stream>>>(ep, deg_src_all, cursor_all, csrc_all,
                                                csw_all, eps, x, sxl);
  {
    WComb wc;
    for (int l = 0; l < 4; l++) { wc.w[l] = enc_w[l]; wc.c[l] = comb[l]; }
    for (int l = 0; l < 4; l++) { wc.w[4 + l] = dec_w[l]; wc.c[4 + l] = comb[4 + l]; }
    k_combine<<<grid1(18528), WG, 0, stream>>>(wc);
  }

  float* mu_out = (float*)d_out + 960000;
  float* lv_out = (float*)d_out + 961024;

  if (fused) {
    // ---- encoder ----
    float* Ya[5] = {s1, s2, s3, s4, s5};
    run_cheb6<3>(sxl, s0, Ya, comb[0], enc_b[0], 20000, 5000, ds_idx[0], 1,
                 RP(0), CS(0), CW(0), stream);
    run_cheb6<32>(s0, sxl, Ya, comb[1], enc_b[1], 5000, 1250, ds_idx[1], 1,
                  RP(1), CS(1), CW(1), stream);
    run_cheb<32, 64>(sxl, s0, s1, s2, comb[2], enc_b[2], 1250, 313, ds_idx[2], 0,
                     RP(2), CS(2), CW(2), stream);
    run_cheb<64, 64>(s0, s1, s2, s3, comb[3], enc_b[3], 313, 79, ds_idx[3], 0,
                     RP(3), CS(3), CW(3), stream);
    // ---- latent ----
    k_latent<<<1024, 64, 0, stream>>>(s1, mu_w, mu_b, lv_w, lv_b, eps, label, mu_out, lv_out, hcat);
    k_declin<<<grid1(NB * 5056), WG, 0, stream>>>(hcat, dl_w, dl_b, s0);
    // ---- decoder L3, L2, L1 (two-pass) ----
    k_us<64><<<grid1((long)313 * NB * 64), WG, 0, stream>>>(s0, s1, us_idx[3], us_w[3], 313);
    run_cheb<64, 64>(s1, s0, s2, s3, comb[4], dec_b[0], 313, 313, nullptr, 0,
                     RP(3), CS(3), CW(3), stream);
    k_us<64><<<grid1((long)1250 * NB * 64), WG, 0, stream>>>(s0, s1, us_idx[2], us_w[2], 1250);
    run_cheb<64, 64>(s1, s0, s2, s3, comb[5], dec_b[1], 1250, 1250, nullptr, 0,
                     RP(2), CS(2), CW(2), stream);
    k_us<64><<<grid1((long)5000 * NB * 64), WG, 0, stream>>>(s0, s1, us_idx[1], us_w[1], 5000);
    run_cheb<64, 32>(s1, s0, s2, s3, comb[6], dec_b[2], 5000, 5000, nullptr, 0,
                     RP(1), CS(1), CW(1), stream);
    // ---- decoder L0: us0 then single-pass 6-term final ----
    k_us<32><<<grid1((long)20000 * NB * 32), WG, 0, stream>>>(s0, s1, us_idx[0], us_w[0], 20000);
    {
      dim3 gP((unsigned)((20000 + 3) / 4));
      k_propw<32><<<gP, WG, 0, stream>>>(s1, s2, RP(0), CS(0), CW(0), 20000);  // Y1
      k_propw<32><<<gP, WG, 0, stream>>>(s2, s3, RP(0), CS(0), CW(0), 20000);  // Y2
      k_propw<32><<<gP, WG, 0, stream>>>(s3, s4, RP(0), CS(0), CW(0), 20000);  // Y3
      k_propw<32><<<gP, WG, 0, stream>>>(s4, s5, RP(0), CS(0), CW(0), 20000);  // Y4
      k_propw<32><<<gP, WG, 0, stream>>>(s5, s0, RP(0), CS(0), CW(0), 20000);  // Y5
      Ptr6 p{{s1, s2, s3, s4, s5, s0}};
      k_gemm6f<<<320000 / 128, WG, 0, stream>>>(p, comb[7], dec_b[3], dec_w[4],
                                                fixbuf, (float*)d_out, 320000);
    }
  } else {
    // ---- R11 fallback (4 big slots) ----
    run_cheb<3, 32>(sxl, s1, s2, s3, comb[0], enc_b[0], 20000, 5000, ds_idx[0], 0,
                    RP(0), CS(0), CW(0), stream);
    run_cheb<32, 32>(s1, s0, s2, s3, comb[1], enc_b[1], 5000, 1250, ds_idx[1], 0,
                     RP(1), CS(1), CW(1), stream);
    run_cheb<32, 64>(s0, s1, s2, s3, comb[2], enc_b[2], 1250, 313, ds_idx[2], 0,
                     RP(2), CS(2), CW(2), stream);
    run_cheb<64, 64>(s1, s0, s2, s3, comb[3], enc_b[3], 313, 79, ds_idx[3], 0,
                     RP(3), CS(3), CW(3), stream);
    k_latent<<<1024, 64, 0, stream>>>(s0, mu_w, mu_b, lv_w, lv_b, eps, label, mu_out, lv_out, hcat);
    k_declin<<<grid1(NB * 5056), WG, 0, stream>>>(hcat, dl_w, dl_b, s0);
    k_us<64><<<grid1((long)313 * NB * 64), WG, 0, stream>>>(s0, s1, us_idx[3], us_w[3], 313);
    run_cheb<64, 64>(s1, s0, s2, s3, comb[4], dec_b[0], 313, 313, nullptr, 0,
                     RP(3), CS(3), CW(3), stream);
    k_us<64><<<grid1((long)1250 * NB * 64), WG, 0, stream>>>(s0, s1, us_idx[2], us_w[2], 1250);
    run_cheb<64, 64>(s1, s0, s2, s3, comb[5], dec_b[1], 1250, 1250, nullptr, 0,
                     RP(2), CS(2), CW(2), stream);
    k_us<64><<<grid1((long)5000 * NB * 64), WG, 0, stream>>>(s0, s1, us_idx[1], us_w[1], 5000);
    run_cheb<64, 32>(s1, s0, s2, s3, comb[6], dec_b[2], 5000, 5000, nullptr, 0,
                     RP(1), CS(1), CW(1), stream);
    k_us<32><<<grid1((long)20000 * NB * 32), WG, 0, stream>>>(s0, s1, us_idx[0], us_w[0], 20000);
    {
      dim3 gP((unsigned)((20000 + 3) / 4));
      dim3 gG((unsigned)(320000 / 128));
      k_propw<32><<<gP, WG, 0, stream>>>(s1, s2, RP(0), CS(0), CW(0), 20000);
      k_propw<32><<<gP, WG, 0, stream>>>(s2, s3, RP(0), CS(0), CW(0), 20000);
      Ptr3 p1{{s1, s2, s3}};
      k_gemm3<32, 32><<<gG, WG, 0, stream>>>(p1, comb[7], dec_b[3], s0, 320000, nullptr, 0, 0);
      k_propw<32><<<gP, WG, 0, stream>>>(s3, s1, RP(0), CS(0), CW(0), 20000);
      k_propw<32><<<gP, WG, 0, stream>>>(s1, s2, RP(0), CS(0), CW(0), 20000);
      k_propw<32><<<gP, WG, 0, stream>>>(s2, s3, RP(0), CS(0), CW(0), 20000);
      Ptr3 p2{{s1, s2, s3}};
      k_gemm3_final<<<gG, WG, 0, stream>>>(p2, comb[7] + 3 * 32 * 32, dec_w[4], s0,
                                           (float*)d_out, 320000);
    }
    k_final_fix<<<16, 256, 0, stream>>>(s0, dec_w[4], RP(4), CS(4), CW(4), (float*)d_out);
    return;
  }

  // ---- exact 79-node fixup (fused path) ----
  k_final_fix<<<16, 256, 0, stream>>>(fixbuf, dec_w[4], RP(4), CS(4), CW(4), (float*)d_out);
}

// Round 14
// 1131.501 us; speedup vs baseline: 1.4193x; 1.0156x over previous
//
#include <hip/hip_runtime.h>
#include <cstdint>
#include <cstddef>

#define WG 256
#define NB 16  // batch

// Layout "L": arr[(n*16 + b)*F + f]  — node-major, batch, feature.
// Monomial basis: out = sum_j (S^j X) @ C_j (combos via k_combine).
// All fp32. Single-pass 6-term gemm (bitwise identical to two-pass).

struct IP5 { const int* e[5]; };
struct Ptr3 { const float* p[3]; };
struct Ptr6 { const float* p[6]; };
struct WComb { const float* w[8]; float* c[8]; };

static __device__ __forceinline__ void fma4(float4& a, float s, const float4& b) {
  a.x = fmaf(s, b.x, a.x); a.y = fmaf(s, b.y, a.y);
  a.z = fmaf(s, b.z, a.z); a.w = fmaf(s, b.w, a.w);
}

// ---------------- fused setup kernels ----------------

__global__ void k_zero_i(int* __restrict__ p, int n) {
  int i = blockIdx.x * WG + threadIdx.x;
  if (i < n) p[i] = 0;
}

__global__ void k_hist_all(IP5 ep, int* __restrict__ dsrc, int* __restrict__ dtgt) {
  int i = blockIdx.x * WG + threadIdx.x;
  if (i >= 159852) return;
  int l, eo, ee, no, co;
  if (i < 120000)      { l = 0; eo = 0;      ee = 120000; no = 0;     co = 0; }
  else if (i < 150000) { l = 1; eo = 120000; ee = 30000;  no = 20000; co = 20000; }
  else if (i < 157500) { l = 2; eo = 150000; ee = 7500;   no = 25000; co = 25000; }
  else if (i < 159378) { l = 3; eo = 157500; ee = 1878;   no = 26250; co = 26250; }
  else                 { l = 4; eo = 159378; ee = 474;    no = 26563; co = 26563; }
  int e = i - eo;
  const int* E = ep.e[l];
  atomicAdd(&dsrc[no + E[e]], 1);
  atomicAdd(&dtgt[co + E[ee + e]], 1);
}

__global__ void k_scan_all(const int* __restrict__ deg_all, int* __restrict__ rowptr_all,
                           int* __restrict__ cursor_all) {
  static const int Ns[5] = {20000, 5000, 1250, 313, 20000};
  static const int CO[5] = {0, 20000, 25000, 26250, 26563};
  static const int RO[5] = {0, 20001, 25002, 26253, 26567};
  __shared__ int s[WG];
  int l = blockIdx.x;
  int N = Ns[l];
  const int* deg = deg_all + CO[l];
  int* rowptr = rowptr_all + RO[l];
  int* cursor = cursor_all + CO[l];
  int t = threadIdx.x;
  int chunk = (N + WG - 1) / WG;
  int a = t * chunk;
  int b = min(N, a + chunk);
  int sum = 0;
  for (int i = a; i < b; i++) sum += deg[i];
  s[t] = sum;
  __syncthreads();
  for (int off = 1; off < WG; off <<= 1) {
    int v = (t >= off) ? s[t - off] : 0;
    __syncthreads();
    s[t] += v;
    __syncthreads();
  }
  int run = (t == 0) ? 0 : s[t - 1];
  for (int i = a; i < b; i++) {
    rowptr[i] = run;
    cursor[i] = run;
    run += deg[i];
  }
  if (t == 0) rowptr[N] = s[WG - 1];
}

// monomial-basis weight combos for all 8 cheb layers
__global__ void k_combine(WComb wc) {
  static const int M[8] = {96, 1024, 2048, 4096, 4096, 4096, 2048, 1024};
  static const int OFF[8] = {0, 96, 1120, 3168, 7264, 11360, 15456, 17504};
  int i = blockIdx.x * WG + threadIdx.x;
  if (i >= 18528) return;
  int l = 0;
  while (l < 7 && i >= OFF[l + 1]) l++;
  int e = i - OFF[l], m = M[l];
  const float* w = wc.w[l];
  float* c = wc.c[l];
  float w0 = w[e], w1 = w[m + e], w2 = w[2 * m + e];
  float w3 = w[3 * m + e], w4 = w[4 * m + e], w5 = w[5 * m + e];
  c[e]         = w0 - w2 + w4;
  c[m + e]     = w1 - 3.f * w3 + 5.f * w5;
  c[2 * m + e] = 2.f * w2 - 8.f * w4;
  c[3 * m + e] = 4.f * w3 - 20.f * w5;
  c[4 * m + e] = 8.f * w4;
  c[5 * m + e] = 16.f * w5;
}

// ---------------- threefry eps (verified vs harness JAX ref) ----------------

static __device__ __forceinline__ float erfinv_f(float x) {
  float w = -log1pf(-x * x);
  float p;
  if (w < 5.0f) {
    w -= 2.5f;
    p = 2.81022636e-08f;
    p = fmaf(p, w, 3.43273939e-07f);
    p = fmaf(p, w, -3.5233877e-06f);
    p = fmaf(p, w, -4.39150654e-06f);
    p = fmaf(p, w, 0.00021858087f);
    p = fmaf(p, w, -0.00125372503f);
    p = fmaf(p, w, -0.00417768164f);
    p = fmaf(p, w, 0.246640727f);
    p = fmaf(p, w, 1.50140941f);
  } else {
    w = sqrtf(w) - 3.0f;
    p = -0.000200214257f;
    p = fmaf(p, w, 0.000100950558f);
    p = fmaf(p, w, 0.00134934322f);
    p = fmaf(p, w, -0.00367342844f);
    p = fmaf(p, w, 0.00573950773f);
    p = fmaf(p, w, -0.0076224613f);
    p = fmaf(p, w, 0.00943887047f);
    p = fmaf(p, w, 1.00167406f);
    p = fmaf(p, w, 2.83297682f);
  }
  return p * x;
}

static __device__ __forceinline__ float bits_to_normal(unsigned b) {
  float f = __uint_as_float((b >> 9) | 0x3f800000u) - 1.0f;
  const float lo = -0.99999994f;
  float u = f * (1.0f - lo) + lo;
  u = fmaxf(u, lo);
  return 1.41421356f * erfinv_f(u);
}

static __device__ __forceinline__ float eps_val(int i) {
  unsigned x0 = 0u, x1 = (unsigned)i;
  unsigned ks[3] = {0u, 42u, 0u ^ 42u ^ 0x1BD11BDAu};
  x0 += ks[0];
  x1 += ks[1];
  const int R[2][4] = {{13, 15, 26, 6}, {17, 29, 16, 24}};
#pragma unroll
  for (int it = 0; it < 5; it++) {
#pragma unroll
    for (int j = 0; j < 4; j++) {
      x0 += x1;
      int r = R[it & 1][j];
      x1 = (x1 << r) | (x1 >> (32 - r));
      x1 ^= x0;
    }
    x0 += ks[(it + 1) % 3];
    x1 += ks[(it + 2) % 3] + (unsigned)(it + 1);
  }
  return bits_to_normal(x0 ^ x1);
}

__global__ void k_fill_all(IP5 ep, const int* __restrict__ dsrc, int* __restrict__ cursor,
                           int* __restrict__ csrc, float* __restrict__ csw,
                           float* __restrict__ eps, const float* __restrict__ x,
                           float* __restrict__ sxl) {
  int blk = blockIdx.x;
  if (blk < 625) {
    int i = blk * WG + threadIdx.x;
    if (i >= 159852) return;
    int l, eo, ee, no, co, eb;
    if (i < 120000)      { l = 0; eo = 0;      ee = 120000; no = 0;     co = 0;     eb = 0; }
    else if (i < 150000) { l = 1; eo = 120000; ee = 30000;  no = 20000; co = 20000; eb = 120000; }
    else if (i < 157500) { l = 2; eo = 150000; ee = 7500;   no = 25000; co = 25000; eb = 150000; }
    else if (i < 159378) { l = 3; eo = 157500; ee = 1878;   no = 26250; co = 26250; eb = 157500; }
    else                 { l = 4; eo = 159378; ee = 474;    no = 26563; co = 26563; eb = 159378; }
    int e = i - eo;
    const int* E = ep.e[l];
    int s = E[e], t = E[ee + e];
    float da = (float)dsrc[no + s], db = (float)dsrc[no + t];
    float wa = (da > 0.f) ? (1.0f / sqrtf(da)) : 0.f;
    float wb = (db > 0.f) ? (1.0f / sqrtf(db)) : 0.f;
    int pos = atomicAdd(&cursor[co + t], 1);
    csrc[eb + pos] = s;
    csw[eb + pos] = wa * wb;
  } else if (blk < 629) {
    int j = (blk - 625) * WG + threadIdx.x;
    if (j < 1024) eps[j] = eps_val(j);
  } else {
    int j = (blk - 629) * WG + threadIdx.x;
    if (j >= NB * 20000 * 3) return;
    int f = j % 3;
    int b = (j / 3) % NB;
    int n = j / 48;
    sxl[j] = x[((size_t)b * 20000 + n) * 3 + f];
  }
}

// ---------------- wave-per-node propagation: out = S * in ----------------

#define RFL_I(v) __builtin_amdgcn_readfirstlane(v)
#define RFL_F(v) __int_as_float(__builtin_amdgcn_readfirstlane(__float_as_int(v)))

template <int F>
__global__ __launch_bounds__(WG) void k_propw(const float* __restrict__ in,
                                              float* __restrict__ out,
                                              const int* __restrict__ rowptr,
                                              const int* __restrict__ csrc,
                                              const float* __restrict__ csw, int N) {
  constexpr int C4 = F / 16;
  int node = blockIdx.x * 4 + (threadIdx.x >> 6);
  if (node >= N) return;
  int lane = threadIdx.x & 63;
  const float4* in4 = (const float4*)in;
  float4 acc[C4];
#pragma unroll
  for (int u = 0; u < C4; u++) acc[u] = make_float4(0.f, 0.f, 0.f, 0.f);
  int beg = rowptr[node], end = rowptr[node + 1];
  int j = beg;
  for (; j + 3 < end; j += 4) {
    int s0 = RFL_I(csrc[j]);
    int s1 = RFL_I(csrc[j + 1]);
    int s2 = RFL_I(csrc[j + 2]);
    int s3 = RFL_I(csrc[j + 3]);
    float w0 = RFL_F(csw[j]);
    float w1 = RFL_F(csw[j + 1]);
    float w2 = RFL_F(csw[j + 2]);
    float w3 = RFL_F(csw[j + 3]);
    const float4* p0 = in4 + (size_t)s0 * (4 * F) + lane;
    const float4* p1 = in4 + (size_t)s1 * (4 * F) + lane;
    const float4* p2 = in4 + (size_t)s2 * (4 * F) + lane;
    const float4* p3 = in4 + (size_t)s3 * (4 * F) + lane;
    float4 v0[C4], v1[C4], v2[C4], v3[C4];
#pragma unroll
    for (int u = 0; u < C4; u++) v0[u] = p0[u * 64];
#pragma unroll
    for (int u = 0; u < C4; u++) v1[u] = p1[u * 64];
#pragma unroll
    for (int u = 0; u < C4; u++) v2[u] = p2[u * 64];
#pragma unroll
    for (int u = 0; u < C4; u++) v3[u] = p3[u * 64];
#pragma unroll
    for (int u = 0; u < C4; u++) {
      fma4(acc[u], w0, v0[u]);
      fma4(acc[u], w1, v1[u]);
      fma4(acc[u], w2, v2[u]);
      fma4(acc[u], w3, v3[u]);
    }
  }
  for (; j < end; j++) {
    int s0 = RFL_I(csrc[j]);
    float w0 = RFL_F(csw[j]);
    const float4* p0 = in4 + (size_t)s0 * (4 * F) + lane;
#pragma unroll
    for (int u = 0; u < C4; u++) {
      float4 v0 = p0[u * 64];
      fma4(acc[u], w0, v0);
    }
  }
  float4* o4 = (float4*)out + (size_t)node * (4 * F) + lane;
#pragma unroll
  for (int u = 0; u < C4; u++) o4[u * 64] = acc[u];
}

// F=3 variant
__global__ __launch_bounds__(WG) void k_propw3(const float* __restrict__ in,
                                               float* __restrict__ out,
                                               const int* __restrict__ rowptr,
                                               const int* __restrict__ csrc,
                                               const float* __restrict__ csw, int N) {
  int node = blockIdx.x * 4 + (threadIdx.x >> 6);
  if (node >= N) return;
  int lane = threadIdx.x & 63;
  if (lane >= 48) return;
  float acc = 0.f;
  int beg = rowptr[node], end = rowptr[node + 1];
  for (int j = beg; j < end; j++) {
    int s = RFL_I(csrc[j]);
    float w = RFL_F(csw[j]);
    acc = fmaf(w, in[(size_t)s * 48 + lane], acc);
  }
  out[(size_t)node * 48 + lane] = acc;
}

// ---------------- fused 3-term GEMM, 4 rows x 4 cols per thread ----------------

template <int F, int G>
__global__ __launch_bounds__(WG) void k_gemm3(Ptr3 txs, const float* __restrict__ W,
                                              const float* __restrict__ bias,
                                              float* __restrict__ out, int rows,
                                              const int* __restrict__ idx,
                                              int accum, int relu) {
  constexpr int CG = G / 4;
  constexpr int RT = WG / CG;
  constexpr int RPB = RT * 4;
  __shared__ float sW[3 * F * G];
  for (int i = threadIdx.x; i < 3 * F * G; i += WG) sW[i] = W[i];
  __syncthreads();
  int cg = threadIdx.x % CG;
  int rt = threadIdx.x / CG;
  int row0 = blockIdx.x * RPB + rt * 4;
  if (row0 >= rows) return;
  size_t src0 = row0;
  if (idx) {
    int node = row0 >> 4, b = row0 & 15;
    src0 = (size_t)idx[node] * 16 + b;
  }
  float* o = out + (size_t)row0 * G + cg * 4;
  float4 acc[4];
  if (accum) {
#pragma unroll
    for (int r = 0; r < 4; r++) acc[r] = *(const float4*)(o + (size_t)r * G);
  } else if (bias) {
    float4 bv = *(const float4*)(bias + cg * 4);
#pragma unroll
    for (int r = 0; r < 4; r++) acc[r] = bv;
  } else {
#pragma unroll
    for (int r = 0; r < 4; r++) acc[r] = make_float4(0.f, 0.f, 0.f, 0.f);
  }
#pragma unroll
  for (int kk = 0; kk < 3; kk++) {
    const float* tb = txs.p[kk] + src0 * F;
    const float* w = sW + kk * F * G + cg * 4;
    if constexpr (F == 3) {
      float4 w0 = *(const float4*)(w + 0 * G);
      float4 w1 = *(const float4*)(w + 1 * G);
      float4 w2 = *(const float4*)(w + 2 * G);
#pragma unroll
      for (int r = 0; r < 4; r++) {
        float x0 = tb[r * 3 + 0], x1 = tb[r * 3 + 1], x2 = tb[r * 3 + 2];
        fma4(acc[r], x0, w0);
        fma4(acc[r], x1, w1);
        fma4(acc[r], x2, w2);
      }
    } else {
#pragma unroll
      for (int fg = 0; fg < F / 4; fg++) {
        float4 xv[4];
#pragma unroll
        for (int r = 0; r < 4; r++) xv[r] = *(const float4*)(tb + (size_t)r * F + 4 * fg);
        float4 w0 = *(const float4*)(w + (4 * fg + 0) * G);
        float4 w1 = *(const float4*)(w + (4 * fg + 1) * G);
        float4 w2 = *(const float4*)(w + (4 * fg + 2) * G);
        float4 w3 = *(const float4*)(w + (4 * fg + 3) * G);
#pragma unroll
        for (int r = 0; r < 4; r++) {
          fma4(acc[r], xv[r].x, w0);
          fma4(acc[r], xv[r].y, w1);
          fma4(acc[r], xv[r].z, w2);
          fma4(acc[r], xv[r].w, w3);
        }
      }
    }
  }
  if (relu) {
#pragma unroll
    for (int r = 0; r < 4; r++) {
      acc[r].x = fmaxf(acc[r].x, 0.f); acc[r].y = fmaxf(acc[r].y, 0.f);
      acc[r].z = fmaxf(acc[r].z, 0.f); acc[r].w = fmaxf(acc[r].w, 0.f);
    }
  }
#pragma unroll
  for (int r = 0; r < 4; r++) *(float4*)(o + (size_t)r * G) = acc[r];
}

// ---------------- single-pass 6-term GEMM, G=32 (F=3, 32 or 64) ----------------

template <int F>
__global__ __launch_bounds__(WG) void k_gemm6(Ptr6 txs, const float* __restrict__ W,
                                              const float* __restrict__ bias,
                                              float* __restrict__ out, int rows,
                                              const int* __restrict__ idx, int relu) {
  constexpr int G = 32;
  __shared__ float sW[6 * F * G];
  for (int i = threadIdx.x; i < 6 * F * G; i += WG) sW[i] = W[i];
  __syncthreads();
  int cg = threadIdx.x & 7;
  int rt = threadIdx.x >> 3;
  int row0 = blockIdx.x * 128 + rt * 4;
  if (row0 >= rows) return;
  size_t src0 = row0;
  if (idx) {
    int node = row0 >> 4, b = row0 & 15;
    src0 = (size_t)idx[node] * 16 + b;
  }
  float* o = out + (size_t)row0 * G + cg * 4;
  float4 acc[4];
  float4 bv = *(const float4*)(bias + cg * 4);
#pragma unroll
  for (int r = 0; r < 4; r++) acc[r] = bv;
#pragma unroll
  for (int kk = 0; kk < 6; kk++) {
    const float* tb = txs.p[kk] + src0 * F;
    const float* w = sW + kk * F * G + cg * 4;
    if constexpr (F == 3) {
      float4 w0 = *(const float4*)(w + 0 * G);
      float4 w1 = *(const float4*)(w + 1 * G);
      float4 w2 = *(const float4*)(w + 2 * G);
#pragma unroll
      for (int r = 0; r < 4; r++) {
        float x0 = tb[r * 3 + 0], x1 = tb[r * 3 + 1], x2 = tb[r * 3 + 2];
        fma4(acc[r], x0, w0);
        fma4(acc[r], x1, w1);
        fma4(acc[r], x2, w2);
      }
    } else {
#pragma unroll
      for (int fg = 0; fg < F / 4; fg++) {
        float4 xv[4];
#pragma unroll
        for (int r = 0; r < 4; r++) xv[r] = *(const float4*)(tb + (size_t)r * F + 4 * fg);
        float4 w0 = *(const float4*)(w + (4 * fg + 0) * G);
        float4 w1 = *(const float4*)(w + (4 * fg + 1) * G);
        float4 w2 = *(const float4*)(w + (4 * fg + 2) * G);
        float4 w3 = *(const float4*)(w + (4 * fg + 3) * G);
#pragma unroll
        for (int r = 0; r < 4; r++) {
          fma4(acc[r], xv[r].x, w0);
          fma4(acc[r], xv[r].y, w1);
          fma4(acc[r], xv[r].z, w2);
          fma4(acc[r], xv[r].w, w3);
        }
      }
    }
  }
  if (relu) {
#pragma unroll
    for (int r = 0; r < 4; r++) {
      acc[r].x = fmaxf(acc[r].x, 0.f); acc[r].y = fmaxf(acc[r].y, 0.f);
      acc[r].z = fmaxf(acc[r].z, 0.f); acc[r].w = fmaxf(acc[r].w, 0.f);
    }
  }
#pragma unroll
  for (int r = 0; r < 4; r++) *(float4*)(o + (size_t)r * G) = acc[r];
}

// ---- decoder L0 single-pass: 6 terms + bias + relu + level-4 shortcut ----
__global__ __launch_bounds__(WG) void k_gemm6f(Ptr6 txs, const float* __restrict__ W,
                                               const float* __restrict__ bias,
                                               const float* __restrict__ W4,
                                               float* __restrict__ fixbuf,
                                               float* __restrict__ dout, int rows) {
  constexpr int F = 32, G = 32;
  __shared__ float sW[6 * F * G];
  __shared__ float sWc[96];
  for (int i = threadIdx.x; i < 6 * F * G; i += WG) sW[i] = W[i];
  if (threadIdx.x < 96)
    sWc[threadIdx.x] = W4[threadIdx.x] - W4[192 + threadIdx.x] + W4[384 + threadIdx.x];
  __syncthreads();
  int cg = threadIdx.x & 7;
  int rt = threadIdx.x >> 3;
  int row0 = blockIdx.x * 128 + rt * 4;
  float4 acc[4];
  float4 bv = *(const float4*)(bias + cg * 4);
#pragma unroll
  for (int r = 0; r < 4; r++) acc[r] = bv;
#pragma unroll
  for (int kk = 0; kk < 6; kk++) {
    const float* tb = txs.p[kk] + (size_t)row0 * F;
    const float* w = sW + kk * F * G + cg * 4;
#pragma unroll
    for (int fg = 0; fg < F / 4; fg++) {
      float4 xv[4];
#pragma unroll
      for (int r = 0; r < 4; r++) xv[r] = *(const float4*)(tb + (size_t)r * F + 4 * fg);
      float4 w0 = *(const float4*)(w + (4 * fg + 0) * G);
      float4 w1 = *(const float4*)(w + (4 * fg + 1) * G);
      float4 w2 = *(const float4*)(w + (4 * fg + 2) * G);
      float4 w3 = *(const float4*)(w + (4 * fg + 3) * G);
#pragma unroll
      for (int r = 0; r < 4; r++) {
        fma4(acc[r], xv[r].x, w0);
        fma4(acc[r], xv[r].y, w1);
        fma4(acc[r], xv[r].z, w2);
        fma4(acc[r], xv[r].w, w3);
      }
    }
  }
#pragma unroll
  for (int r = 0; r < 4; r++) {
    acc[r].x = fmaxf(acc[r].x, 0.f); acc[r].y = fmaxf(acc[r].y, 0.f);
    acc[r].z = fmaxf(acc[r].z, 0.f); acc[r].w = fmaxf(acc[r].w, 0.f);
  }
  if ((row0 >> 4) < 79) {
#pragma unroll
    for (int r = 0; r < 4; r++)
      *(float4*)(fixbuf + (size_t)(row0 + r) * 32 + cg * 4) = acc[r];
  }
#pragma unroll
  for (int r = 0; r < 4; r++) {
    float av[4] = {acc[r].x, acc[r].y, acc[r].z, acc[r].w};
    float p0 = 0.f, p1 = 0.f, p2 = 0.f;
#pragma unroll
    for (int j = 0; j < 4; j++) {
      int f = cg * 4 + j;
      p0 = fmaf(av[j], sWc[f * 3 + 0], p0);
      p1 = fmaf(av[j], sWc[f * 3 + 1], p1);
      p2 = fmaf(av[j], sWc[f * 3 + 2], p2);
    }
#pragma unroll
    for (int m = 4; m >= 1; m >>= 1) {
      p0 += __shfl_xor(p0, m, 64);
      p1 += __shfl_xor(p1, m, 64);
      p2 += __shfl_xor(p2, m, 64);
    }
    if (cg == 0) {
      int row = row0 + r;
      int n = row >> 4, b = row & 15;
      float* od = dout + ((size_t)b * 20000 + n) * 3;
      od[0] = p0; od[1] = p1; od[2] = p2;
    }
  }
}

// two-pass L0 pass2 (fallback path)
__global__ __launch_bounds__(WG) void k_gemm3_final(Ptr3 txs, const float* __restrict__ W,
                                                    const float* __restrict__ W4,
                                                    float* __restrict__ out,
                                                    float* __restrict__ dout, int rows) {
  constexpr int F = 32, G = 32;
  __shared__ float sW[3 * F * G];
  __shared__ float sWc[96];
  for (int i = threadIdx.x; i < 3 * F * G; i += WG) sW[i] = W[i];
  if (threadIdx.x < 96)
    sWc[threadIdx.x] = W4[threadIdx.x] - W4[192 + threadIdx.x] + W4[384 + threadIdx.x];
  __syncthreads();
  int cg = threadIdx.x & 7;
  int rt = threadIdx.x >> 3;
  int row0 = blockIdx.x * 128 + rt * 4;
  float* o = out + (size_t)row0 * G + cg * 4;
  float4 acc[4];
#pragma unroll
  for (int r = 0; r < 4; r++) acc[r] = *(const float4*)(o + (size_t)r * G);
#pragma unroll
  for (int kk = 0; kk < 3; kk++) {
    const float* tb = txs.p[kk] + (size_t)row0 * F;
    const float* w = sW + kk * F * G + cg * 4;
#pragma unroll
    for (int fg = 0; fg < F / 4; fg++) {
      float4 xv[4];
#pragma unroll
      for (int r = 0; r < 4; r++) xv[r] = *(const float4*)(tb + (size_t)r * F + 4 * fg);
      float4 w0 = *(const float4*)(w + (4 * fg + 0) * G);
      float4 w1 = *(const float4*)(w + (4 * fg + 1) * G);
      float4 w2 = *(const float4*)(w + (4 * fg + 2) * G);
      float4 w3 = *(const float4*)(w + (4 * fg + 3) * G);
#pragma unroll
      for (int r = 0; r < 4; r++) {
        fma4(acc[r], xv[r].x, w0);
        fma4(acc[r], xv[r].y, w1);
        fma4(acc[r], xv[r].z, w2);
        fma4(acc[r], xv[r].w, w3);
      }
    }
  }
#pragma unroll
  for (int r = 0; r < 4; r++) {
    acc[r].x = fmaxf(acc[r].x, 0.f); acc[r].y = fmaxf(acc[r].y, 0.f);
    acc[r].z = fmaxf(acc[r].z, 0.f); acc[r].w = fmaxf(acc[r].w, 0.f);
  }
  if ((row0 >> 4) < 79) {
#pragma unroll
    for (int r = 0; r < 4; r++) *(float4*)(o + (size_t)r * G) = acc[r];
  }
#pragma unroll
  for (int r = 0; r < 4; r++) {
    float av[4] = {acc[r].x, acc[r].y, acc[r].z, acc[r].w};
    float p0 = 0.f, p1 = 0.f, p2 = 0.f;
#pragma unroll
    for (int j = 0; j < 4; j++) {
      int f = cg * 4 + j;
      p0 = fmaf(av[j], sWc[f * 3 + 0], p0);
      p1 = fmaf(av[j], sWc[f * 3 + 1], p1);
      p2 = fmaf(av[j], sWc[f * 3 + 2], p2);
    }
#pragma unroll
    for (int m = 4; m >= 1; m >>= 1) {
      p0 += __shfl_xor(p0, m, 64);
      p1 += __shfl_xor(p1, m, 64);
      p2 += __shfl_xor(p2, m, 64);
    }
    if (cg == 0) {
      int row = row0 + r;
      int n = row >> 4, b = row & 15;
      float* od = dout + ((size_t)b * 20000 + n) * 3;
      od[0] = p0; od[1] = p1; od[2] = p2;
    }
  }
}

// exact K=6 Chebyshev fixup for the 79 real nodes (fp32 in, T-basis).
__global__ __launch_bounds__(256) void k_final_fix(const float* __restrict__ in,
                                                   const float* __restrict__ W,  // 6x32x3
                                                   const int* __restrict__ rowptr,
                                                   const int* __restrict__ csrc,
                                                   const float* __restrict__ csw,
                                                   float* __restrict__ out) {
  __shared__ float B0[79 * 32], B1[79 * 32], B2[79 * 32];
  __shared__ float sacc[79 * 3];
  __shared__ float sW[576];
  int b = blockIdx.x, t = threadIdx.x;
  for (int i = t; i < 576; i += 256) sW[i] = W[i];
  for (int i = t; i < 2528; i += 256) {
    int r = i >> 5, f = i & 31;
    B0[i] = in[((size_t)r * 16 + b) * 32 + f];
  }
  __syncthreads();
  for (int i = t; i < 237; i += 256) {
    int r = i / 3, g = i % 3;
    float a = 0.f;
    for (int f = 0; f < 32; f++) a = fmaf(B0[r * 32 + f], sW[f * 3 + g], a);
    sacc[i] = a;
  }
  for (int i = t; i < 2528; i += 256) {
    int r = i >> 5, f = i & 31;
    float a = 0.f;
    for (int j = rowptr[r]; j < rowptr[r + 1]; j++) a = fmaf(csw[j], B0[csrc[j] * 32 + f], a);
    B1[i] = a;
  }
  __syncthreads();
  for (int i = t; i < 237; i += 256) {
    int r = i / 3, g = i % 3;
    float a = sacc[i];
    for (int f = 0; f < 32; f++) a = fmaf(B1[r * 32 + f], sW[96 + f * 3 + g], a);
    sacc[i] = a;
  }
  for (int i = t; i < 2528; i += 256) {
    int r = i >> 5, f = i & 31;
    float a = 0.f;
    for (int j = rowptr[r]; j < rowptr[r + 1]; j++) a = fmaf(csw[j], B1[csrc[j] * 32 + f], a);
    B2[i] = 2.f * a - B0[i];
  }
  __syncthreads();
  for (int i = t; i < 237; i += 256) {
    int r = i / 3, g = i % 3;
    float a = sacc[i];
    for (int f = 0; f < 32; f++) a = fmaf(B2[r * 32 + f], sW[192 + f * 3 + g], a);
    sacc[i] = a;
  }
  __syncthreads();
  for (int i = t; i < 2528; i += 256) {
    int r = i >> 5, f = i & 31;
    float a = 0.f;
    for (int j = rowptr[r]; j < rowptr[r + 1]; j++) a = fmaf(csw[j], B2[csrc[j] * 32 + f], a);
    B0[i] = 2.f * a - B1[i];
  }
  __syncthreads();
  for (int i = t; i < 237; i += 256) {
    int r = i / 3, g = i % 3;
    float a = sacc[i];
    for (int f = 0; f < 32; f++) a = fmaf(B0[r * 32 + f], sW[288 + f * 3 + g], a);
    sacc[i] = a;
  }
  __syncthreads();
  for (int i = t; i < 2528; i += 256) {
    int r = i >> 5, f = i & 31;
    float a = 0.f;
    for (int j = rowptr[r]; j < rowptr[r + 1]; j++) a = fmaf(csw[j], B0[csrc[j] * 32 + f], a);
    B1[i] = 2.f * a - B2[i];
  }
  __syncthreads();
  for (int i = t; i < 237; i += 256) {
    int r = i / 3, g = i % 3;
    float a = sacc[i];
    for (int f = 0; f < 32; f++) a = fmaf(B1[r * 32 + f], sW[384 + f * 3 + g], a);
    sacc[i] = a;
  }
  __syncthreads();
  for (int i = t; i < 2528; i += 256) {
    int r = i >> 5, f = i & 31;
    float a = 0.f;
    for (int j = rowptr[r]; j < rowptr[r + 1]; j++) a = fmaf(csw[j], B1[csrc[j] * 32 + f], a);
    B2[i] = 2.f * a - B0[i];
  }
  __syncthreads();
  for (int i = t; i < 237; i += 256) {
    int r = i / 3, g = i % 3;
    float a = sacc[i];
    for (int f = 0; f < 32; f++) a = fmaf(B2[r * 32 + f], sW[480 + f * 3 + g], a);
    out[((size_t)b * 20000 + r) * 3 + g] = a;
  }
}

// upsample scalar (fallback path)
template <int F>
__global__ __launch_bounds__(WG) void k_us(const float* __restrict__ in,
                                           float* __restrict__ out,
                                           const int* __restrict__ uidx,
                                           const float* __restrict__ uw, int Nf) {
  int i = blockIdx.x * WG + threadIdx.x;
  int total = Nf * NB * F;
  if (i >= total) return;
  int pos = i % (NB * F);
  int r = i / (NB * F);
  float acc = 0.f;
#pragma unroll
  for (int k = 0; k < 3; k++) {
    float v = in[(size_t)uidx[r * 3 + k] * NB * F + pos];
    acc = fmaf(uw[r * 3 + k], fmaxf(v, 0.f), acc);
  }
  out[i] = acc;
}

// upsample float4: 4 elems/thread (NB*F % 4 == 0). relu fused on input.
template <int F>
__global__ __launch_bounds__(WG) void k_us4(const float* __restrict__ in,
                                            float* __restrict__ out,
                                            const int* __restrict__ uidx,
                                            const float* __restrict__ uw, int Nf) {
  constexpr int QR = NB * F / 4;  // float4s per row
  int i = blockIdx.x * WG + threadIdx.x;
  int total = Nf * QR;
  if (i >= total) return;
  int q = i % QR;
  int r = i / QR;
  float4 acc = make_float4(0.f, 0.f, 0.f, 0.f);
#pragma unroll
  for (int k = 0; k < 3; k++) {
    float4 v = ((const float4*)in)[(size_t)uidx[r * 3 + k] * QR + q];
    float wv = uw[r * 3 + k];
    acc.x = fmaf(wv, fmaxf(v.x, 0.f), acc.x);
    acc.y = fmaf(wv, fmaxf(v.y, 0.f), acc.y);
    acc.z = fmaf(wv, fmaxf(v.z, 0.f), acc.z);
    acc.w = fmaf(wv, fmaxf(v.w, 0.f), acc.w);
  }
  ((float4*)out)[(size_t)r * QR + q] = acc;
}

// ---------------- latent kernels (L layout h: (79,16,64)) ----------------

__global__ __launch_bounds__(64) void k_latent(const float* __restrict__ h,
                                               const float* __restrict__ muW,
                                               const float* __restrict__ muB,
                                               const float* __restrict__ lvW,
                                               const float* __restrict__ lvB,
                                               const float* __restrict__ eps,
                                               const float* __restrict__ label,
                                               float* __restrict__ mu_out,
                                               float* __restrict__ lv_out,
                                               float* __restrict__ hcat) {
  int b = blockIdx.x / 64;
  int g = blockIdx.x % 64;
  int l = threadIdx.x;
  float am = 0.f, al = 0.f;
  for (int i = l; i < 5056; i += 64) {
    int n = i >> 6, f = i & 63;
    float hv = h[(size_t)(n * 16 + b) * 64 + f];
    am = fmaf(hv, muW[(size_t)i * 64 + g], am);
    al = fmaf(hv, lvW[(size_t)i * 64 + g], al);
  }
  for (int off = 32; off > 0; off >>= 1) {
    am += __shfl_down(am, off, 64);
    al += __shfl_down(al, off, 64);
  }
  if (l == 0) {
    am += muB[g];
    al += lvB[g];
    mu_out[b * 64 + g] = am;
    lv_out[b * 64 + g] = al;
    hcat[b * 66 + g] = fmaf(eps[b * 64 + g], expf(0.5f * al), am);
    if (g < 2) hcat[b * 66 + 64 + g] = label[b * 2 + g];
  }
}

__global__ __launch_bounds__(WG) void k_declin(const float* __restrict__ hcat,
                                               const float* __restrict__ W,
                                               const float* __restrict__ bias,
                                               float* __restrict__ out) {
  int idx = blockIdx.x * WG + threadIdx.x;
  if (idx >= NB * 5056) return;
  int b = idx / 5056, j = idx % 5056;
  int n = j >> 6, f = j & 63;
  float acc = bias[j];
  const float* hc = hcat + b * 66;
#pragma unroll
  for (int i = 0; i < 66; i++) acc = fmaf(hc[i], W[(size_t)i * 5056 + j], acc);
  out[(size_t)(n * 16 + b) * 64 + f] = fmaxf(acc, 0.f);
}

// ---------------- host orchestration ----------------

static inline dim3 grid1(long n) { return dim3((unsigned)((n + WG - 1) / WG)); }

// two-pass monomial cheb layer
template <int F, int G>
static void run_cheb(float* in, float* out, float* A, float* B,
                     const float* C, const float* bias, int N, int Nout,
                     const int* ds_idx, int relu_last,
                     const int* rowptr, const int* csrc, const float* csw,
                     hipStream_t st) {
  int orows = NB * Nout;
  dim3 gP((unsigned)((N + 3) / 4));
  constexpr int RPB = (WG / (G / 4)) * 4;
  dim3 gG((unsigned)((orows + RPB - 1) / RPB));
  int relu2 = ds_idx ? 1 : relu_last;
  if constexpr (F == 3) {
    k_propw3<<<gP, WG, 0, st>>>(in, A, rowptr, csrc, csw, N);
    k_propw3<<<gP, WG, 0, st>>>(A, B, rowptr, csrc, csw, N);
    Ptr3 p1{{in, A, B}};
    k_gemm3<F, G><<<gG, WG, 0, st>>>(p1, C, bias, out, orows, ds_idx, 0, 0);
    k_propw3<<<gP, WG, 0, st>>>(B, in, rowptr, csrc, csw, N);
    k_propw3<<<gP, WG, 0, st>>>(in, A, rowptr, csrc, csw, N);
    k_propw3<<<gP, WG, 0, st>>>(A, B, rowptr, csrc, csw, N);
    Ptr3 p2{{in, A, B}};
    k_gemm3<F, G><<<gG, WG, 0, st>>>(p2, C + 3 * F * G, nullptr, out, orows, ds_idx, 1, relu2);
  } else {
    k_propw<F><<<gP, WG, 0, st>>>(in, A, rowptr, csrc, csw, N);
    k_propw<F><<<gP, WG, 0, st>>>(A, B, rowptr, csrc, csw, N);
    Ptr3 p1{{in, A, B}};
    k_gemm3<F, G><<<gG, WG, 0, st>>>(p1, C, bias, out, orows, ds_idx, 0, 0);
    k_propw<F><<<gP, WG, 0, st>>>(B, in, rowptr, csrc, csw, N);
    k_propw<F><<<gP, WG, 0, st>>>(in, A, rowptr, csrc, csw, N);
    k_propw<F><<<gP, WG, 0, st>>>(A, B, rowptr, csrc, csw, N);
    Ptr3 p2{{in, A, B}};
    k_gemm3<F, G><<<gG, WG, 0, st>>>(p2, C + 3 * F * G, nullptr, out, orows, ds_idx, 1, relu2);
  }
}

// single-pass cheb layer (G=32): 5 props into Y[0..4]=Y1..Y5, one gemm6
template <int F>
static void run_cheb6(float* in, float* out, float* const* Y,
                      const float* C, const float* bias, int N, int Nout,
                      const int* ds_idx, int relu,
                      const int* rowptr, const int* csrc, const float* csw,
                      hipStream_t st) {
  int orows = NB * Nout;
  dim3 gP((unsigned)((N + 3) / 4));
  dim3 gG((unsigned)((orows + 127) / 128));
  if constexpr (F == 3) {
    k_propw3<<<gP, WG, 0, st>>>(in, Y[0], rowptr, csrc, csw, N);
    k_propw3<<<gP, WG, 0, st>>>(Y[0], Y[1], rowptr, csrc, csw, N);
    k_propw3<<<gP, WG, 0, st>>>(Y[1], Y[2], rowptr, csrc, csw, N);
    k_propw3<<<gP, WG, 0, st>>>(Y[2], Y[3], rowptr, csrc, csw, N);
    k_propw3<<<gP, WG, 0, st>>>(Y[3], Y[4], rowptr, csrc, csw, N);
  } else {
    k_propw<F><<<gP, WG, 0, st>>>(in, Y[0], rowptr, csrc, csw, N);
    k_propw<F><<<gP, WG, 0, st>>>(Y[0], Y[1], rowptr, csrc, csw, N);
    k_propw<F><<<gP, WG, 0, st>>>(Y[1], Y[2], rowptr, csrc, csw, N);
    k_propw<F><<<gP, WG, 0, st>>>(Y[2], Y[3], rowptr, csrc, csw, N);
    k_propw<F><<<gP, WG, 0, st>>>(Y[3], Y[4], rowptr, csrc, csw, N);
  }
  Ptr6 p{{in, Y[0], Y[1], Y[2], Y[3], Y[4]}};
  k_gemm6<F><<<gG, WG, 0, st>>>(p, C, bias, out, orows, ds_idx, relu);
}

extern "C" void kernel_launch(void* const* d_in, const int* in_sizes, int n_in,
                              void* d_out, int out_size, void* d_ws, size_t ws_size,
                              hipStream_t stream) {
  const float* x = (const float*)d_in[0];
  const float* label = (const float*)d_in[1];
  IP5 ep;
  for (int l = 0; l < 5; l++) ep.e[l] = (const int*)d_in[2 + l];
  const int* ds_idx[4];
  const int* us_idx[4];
  const float* us_w[4];
  for (int i = 0; i < 4; i++) {
    ds_idx[i] = (const int*)d_in[7 + 3 * i];
    us_idx[i] = (const int*)d_in[8 + 3 * i];
    us_w[i] = (const float*)d_in[9 + 3 * i];
  }
  const float* enc_w[4];
  const float* enc_b[4];
  for (int i = 0; i < 4; i++) {
    enc_w[i] = (const float*)d_in[19 + 2 * i];
    enc_b[i] = (const float*)d_in[20 + 2 * i];
  }
  const float* dec_w[5];
  for (int i = 0; i < 5; i++) dec_w[i] = (const float*)d_in[27 + i];
  const float* dec_b[4];
  for (int i = 0; i < 4; i++) dec_b[i] = (const float*)d_in[32 + i];
  const float* mu_w = (const float*)d_in[36];
  const float* mu_b = (const float*)d_in[37];
  const float* lv_w = (const float*)d_in[38];
  const float* lv_b = (const float*)d_in[39];
  const float* dl_w = (const float*)d_in[40];
  const float* dl_b = (const float*)d_in[41];

  float* wsf = (float*)d_ws;
  size_t off = 0;
  auto carve = [&](size_t n) -> float* {
    float* p = wsf + off;
    off += (n + 63) & ~(size_t)63;
    return p;
  };
  const size_t SLOT = 10240000;  // 16*20000*32 floats
  const size_t HALF = SLOT / 2;  // 5000-node F=64 row block
  float* s0 = carve(SLOT);
  float* s1 = carve(SLOT);
  float* s2 = carve(SLOT);
  float* s3 = carve(SLOT);
  float* sxl = carve(960000);
  int* deg_all = (int*)carve(26642 + 46563);
  int* deg_src_all = deg_all;
  int* deg_tgt_all = deg_all + 26642;
  int* rowptr_all = (int*)carve(46568);
  int* cursor_all = (int*)carve(46563);
  int* csrc_all = (int*)carve(159852);
  float* csw_all = carve(159852);
  float* eps = carve(1024);
  float* hcat = carve(1056);
  float* fixbuf = carve(79 * 16 * 32);
  static const int CM[8] = {96, 1024, 2048, 4096, 4096, 4096, 2048, 1024};
  float* comb[8];
  for (int l = 0; l < 8; l++) comb[l] = carve((size_t)6 * CM[l]);
  // extra big slots for the single-pass (6-buffer) path
  float* s4 = carve(SLOT);
  float* s5 = carve(SLOT);
  bool fused = (off * sizeof(float)) <= ws_size;

  static const int ROFF[5] = {0, 20001, 25002, 26253, 26567};
  static const int EOFF[5] = {0, 120000, 150000, 157500, 159378};
  auto RP = [&](int l) { return rowptr_all + ROFF[l]; };
  auto CS = [&](int l) { return csrc_all + EOFF[l]; };
  auto CW = [&](int l) { return csw_all + EOFF[l]; };

  // ---- setup: 5 launches ----
  k_zero_i<<<grid1(26642 + 46563), WG, 0, stream>>>(deg_all, 26642 + 46563);
  k_hist_all<<<grid1(159852), WG, 0, stream>>>(ep, deg_src_all, deg_tgt_all);
  k_scan_all<<<5, WG, 0, stream>>>(deg_tgt_all, rowptr_all, cursor_all);
  k_fill_all<<<625 + 4 + 3750, WG, 0, stream>>>(ep, deg_src_all, cursor_all, csrc_all,
                                                csw_all, eps, x, sxl);
  {
    WComb wc;
    for (int l = 0; l < 4; l++) { wc.w[l] = enc_w[l]; wc.c[l] = comb[l]; }
    for (int l = 0; l < 4; l++) { wc.w[4 + l] = dec_w[l]; wc.c[4 + l] = comb[4 + l]; }
    k_combine<<<grid1(18528), WG, 0, stream>>>(wc);
  }

  float* mu_out = (float*)d_out + 960000;
  float* lv_out = (float*)d_out + 961024;

  if (fused) {
    // ---- encoder ----
    float* Ya[5] = {s1, s2, s3, s4, s5};
    run_cheb6<3>(sxl, s0, Ya, comb[0], enc_b[0], 20000, 5000, ds_idx[0], 1,
                 RP(0), CS(0), CW(0), stream);
    run_cheb6<32>(s0, sxl, Ya, comb[1], enc_b[1], 5000, 1250, ds_idx[1], 1,
                  RP(1), CS(1), CW(1), stream);
    run_cheb<32, 64>(sxl, s0, s1, s2, comb[2], enc_b[2], 1250, 313, ds_idx[2], 0,
                     RP(2), CS(2), CW(2), stream);
    run_cheb<64, 64>(s0, s1, s2, s3, comb[3], enc_b[3], 313, 79, ds_idx[3], 0,
                     RP(3), CS(3), CW(3), stream);
    // ---- latent ----
    k_latent<<<1024, 64, 0, stream>>>(s1, mu_w, mu_b, lv_w, lv_b, eps, label, mu_out, lv_out, hcat);
    k_declin<<<grid1(NB * 5056), WG, 0, stream>>>(hcat, dl_w, dl_b, s0);
    // ---- decoder L3, L2 (two-pass) ----
    k_us4<64><<<grid1((long)313 * NB * 16), WG, 0, stream>>>(s0, s1, us_idx[3], us_w[3], 313);
    run_cheb<64, 64>(s1, s0, s2, s3, comb[4], dec_b[0], 313, 313, nullptr, 0,
                     RP(3), CS(3), CW(3), stream);
    k_us4<64><<<grid1((long)1250 * NB * 16), WG, 0, stream>>>(s0, s1, us_idx[2], us_w[2], 1250);
    run_cheb<64, 64>(s1, s0, s2, s3, comb[5], dec_b[1], 1250, 1250, nullptr, 0,
                     RP(2), CS(2), CW(2), stream);
    // ---- decoder L1: single-pass via half-slots ----
    {
      float* h0 = s1;
      float* h1 = s1 + HALF;
      float* h2 = s2;
      float* h3 = s2 + HALF;
      float* h4 = s3;
      float* h5 = s3 + HALF;
      k_us4<64><<<grid1((long)5000 * NB * 16), WG, 0, stream>>>(s0, h0, us_idx[1], us_w[1], 5000);
      dim3 gP((unsigned)((5000 + 3) / 4));
      k_propw<64><<<gP, WG, 0, stream>>>(h0, h1, RP(1), CS(1), CW(1), 5000);  // Y1
      k_propw<64><<<gP, WG, 0, stream>>>(h1, h2, RP(1), CS(1), CW(1), 5000);  // Y2
      k_propw<64><<<gP, WG, 0, stream>>>(h2, h3, RP(1), CS(1), CW(1), 5000);  // Y3
      k_propw<64><<<gP, WG, 0, stream>>>(h3, h4, RP(1), CS(1), CW(1), 5000);  // Y4
      k_propw<64><<<gP, WG, 0, stream>>>(h4, h5, RP(1), CS(1), CW(1), 5000);  // Y5
      Ptr6 p{{h0, h1, h2, h3, h4, h5}};
      k_gemm6<64><<<80000 / 128, WG, 0, stream>>>(p, comb[6], dec_b[2], s4, 80000, nullptr, 0);
    }
    // ---- decoder L0: us0 then single-pass 6-term final ----
    k_us4<32><<<grid1((long)20000 * NB * 8), WG, 0, stream>>>(s4, s5, us_idx[0], us_w[0], 20000);
    {
      dim3 gP((unsigned)((20000 + 3) / 4));
      k_propw<32><<<gP, WG, 0, stream>>>(s5, s0, RP(0), CS(0), CW(0), 20000);  // Y1
      k_propw<32><<<gP, WG, 0, stream>>>(s0, s1, RP(0), CS(0), CW(0), 20000);  // Y2
      k_propw<32><<<gP, WG, 0, stream>>>(s1, s2, RP(0), CS(0), CW(0), 20000);  // Y3
      k_propw<32><<<gP, WG, 0, stream>>>(s2, s3, RP(0), CS(0), CW(0), 20000);  // Y4
      k_propw<32><<<gP, WG, 0, stream>>>(s3, s4, RP(0), CS(0), CW(0), 20000);  // Y5
      Ptr6 p{{s5, s0, s1, s2, s3, s4}};
      k_gemm6f<<<320000 / 128, WG, 0, stream>>>(p, comb[7], dec_b[3], dec_w[4],
                                                fixbuf, (float*)d_out, 320000);
    }
  } else {
    // ---- R11 fallback (4 big slots) ----
    run_cheb<3, 32>(sxl, s1, s2, s3, comb[0], enc_b[0], 20000, 5000, ds_idx[0], 0,
                    RP(0), CS(0), CW(0), stream);
    run_cheb<32, 32>(s1, s0, s2, s3, comb[1], enc_b[1], 5000, 1250, ds_idx[1], 0,
                     RP(1), CS(1), CW(1), stream);
    run_cheb<32, 64>(s0, s1, s2, s3, comb[2], enc_b[2], 1250, 313, ds_idx[2], 0,
                     RP(2), CS(2), CW(2), stream);
    run_cheb<64, 64>(s1, s0, s2, s3, comb[3], enc_b[3], 313, 79, ds_idx[3], 0,
                     RP(3), CS(3), CW(3), stream);
    k_latent<<<1024, 64, 0, stream>>>(s0, mu_w, mu_b, lv_w, lv_b, eps, label, mu_out, lv_out, hcat);
    k_declin<<<grid1(NB * 5056), WG, 0, stream>>>(hcat, dl_w, dl_b, s0);
    k_us<64><<<grid1((long)313 * NB * 64), WG, 0, stream>>>(s0, s1, us_idx[3], us_w[3], 313);
    run_cheb<64, 64>(s1, s0, s2, s3, comb[4], dec_b[0], 313, 313, nullptr, 0,
                     RP(3), CS(3), CW(3), stream);
    k_us<64><<<grid1((long)1250 * NB * 64), WG, 0, stream>>>(s0, s1, us_idx[2], us_w[2], 1250);
    run_cheb<64, 64>(s1, s0, s2, s3, comb[5], dec_b[1], 1250, 1250, nullptr, 0,
                     RP(2), CS(2), CW(2), stream);
    k_us<64><<<grid1((long)5000 * NB * 64), WG, 0, stream>>>(s0, s1, us_idx[1], us_w[1], 5000);
    run_cheb<64, 32>(s1, s0, s2, s3, comb[6], dec_b[2], 5000, 5000, nullptr, 0,
                     RP(1), CS(1), CW(1), stream);
    k_us<32><<<grid1((long)20000 * NB * 32), WG, 0, stream>>>(s0, s1, us_idx[0], us_w[0], 20000);
    {
      dim3 gP((unsigned)((20000 + 3) / 4));
      dim3 gG((unsigned)(320000 / 128));
      k_propw<32><<<gP, WG, 0, stream>>>(s1, s2, RP(0), CS(0), CW(0), 20000);
      k_propw<32><<<gP, WG, 0, stream>>>(s2, s3, RP(0), CS(0), CW(0), 20000);
      Ptr3 p1{{s1, s2, s3}};
      k_gemm3<32, 32><<<gG, WG, 0, stream>>>(p1, comb[7], dec_b[3], s0, 320000, nullptr, 0, 0);
      k_propw<32><<<gP, WG, 0, stream>>>(s3, s1, RP(0), CS(0), CW(0), 20000);
      k_propw<32><<<gP, WG, 0, stream>>>(s1, s2, RP(0), CS(0), CW(0), 20000);
      k_propw<32><<<gP, WG, 0, stream>>>(s2, s3, RP(0), CS(0), CW(0), 20000);
      Ptr3 p2{{s1, s2, s3}};
      k_gemm3_final<<<gG, WG, 0, stream>>>(p2, comb[7] + 3 * 32 * 32, dec_w[4], s0,
                                           (float*)d_out, 320000);
    }
    k_final_fix<<<16, 256, 0, stream>>>(s0, dec_w[4], RP(4), CS(4), CW(4), (float*)d_out);
    return;
  }

  // ---- exact 79-node fixup (fused path) ----
  k_final_fix<<<16, 256, 0, stream>>>(fixbuf, dec_w[4], RP(4), CS(4), CW(4), (float*)d_out);
}